// Round 4
// baseline (217.336 us; speedup 1.0000x reference)
//
#include <hip/hip_runtime.h>
#include <hip/hip_bf16.h>

#define EMBED 1024
#define SEQ   4096
#define NBATCH 4
#define HD    64
#define CH    8    // kv tiles (of 64) per attention partition
#define NP    8    // max partitions

typedef __attribute__((ext_vector_type(8))) short s16x8;
typedef __attribute__((ext_vector_type(4))) float f32x4;
typedef __attribute__((ext_vector_type(4))) unsigned int u32x4;

__device__ __forceinline__ short f2bf(float f) {
    unsigned u = __builtin_bit_cast(unsigned, f);
    u += 0x7fffu + ((u >> 16) & 1u);      // round-to-nearest-even
    return (short)(u >> 16);
}
__device__ __forceinline__ float bf2f(short h) {
    unsigned u = ((unsigned)(unsigned short)h) << 16;
    return __builtin_bit_cast(float, u);
}

typedef const unsigned int __attribute__((address_space(1)))* gbl_ptr_t;
typedef unsigned int __attribute__((address_space(3)))* lds_ptr_t;
__device__ __forceinline__ void async16(const void* g, void* l) {
    __builtin_amdgcn_global_load_lds((gbl_ptr_t)g, (lds_ptr_t)l, 16, 0, 0);
}

// ---------------------------------------------------------------------------
// Kernel 0: W_Q (pre-scaled by 1/8), W_K, W_V fp32 -> bf16 Wb[192][1024]
// ---------------------------------------------------------------------------
__global__ __launch_bounds__(256) void prep_w(
    const float* __restrict__ wq, const float* __restrict__ wk,
    const float* __restrict__ wv, short* __restrict__ Wb)
{
    int idx = blockIdx.x * 256 + threadIdx.x;
    int e = idx * 8;
    int row = e >> 10, col = e & 1023;
    const float* src = (row < 64) ? (wq + (size_t)row * EMBED)
                     : (row < 128) ? (wk + (size_t)(row - 64) * EMBED)
                                   : (wv + (size_t)(row - 128) * EMBED);
    float sc = (row < 64) ? 0.125f : 1.0f;
    float4 f0 = *(const float4*)(src + col);
    float4 f1 = *(const float4*)(src + col + 4);
    s16x8 v = { f2bf(f0.x*sc), f2bf(f0.y*sc), f2bf(f0.z*sc), f2bf(f0.w*sc),
                f2bf(f1.x*sc), f2bf(f1.y*sc), f2bf(f1.z*sc), f2bf(f1.w*sc) };
    *(s16x8*)&Wb[e] = v;
}

// ---------------------------------------------------------------------------
// Kernel 1: QKV projection, depth-2 A-prefetch + double-buffered LDS.
// BM=32, BN=192, BK=64; 4 waves (wr,wc) 2x2, each 16x96; 16 K-iterations.
// ---------------------------------------------------------------------------
__global__ __launch_bounds__(256) void proj_qkv(
    const float* __restrict__ emb, const short* __restrict__ Wb,
    short* __restrict__ Qb, short* __restrict__ Kb, short* __restrict__ Vt)
{
    __shared__ short Alds[2][32 * 64];    // 2 x 4 KB
    __shared__ short Blds[2][192 * 64];   // 2 x 24 KB

    const int tid  = threadIdx.x;
    const int lane = tid & 63;
    const int w    = tid >> 6;
    const int wr   = w & 1;
    const int wc   = w >> 1;
    const int row0 = blockIdx.x * 32;

    const int sr   = tid >> 3;     // staging row 0..31
    const int sg   = tid & 7;      // 16B group 0..7
    const int srow = lane >> 3;
    const int sblk = lane & 7;

    f32x4 acc[6];
#pragma unroll
    for (int i = 0; i < 6; ++i) acc[i] = f32x4{0.f, 0.f, 0.f, 0.f};

    auto stageB = [&](int buf, int t) {
        const int k0 = t * 64;
#pragma unroll
        for (int i = 0; i < 6; ++i) {
            int r = w * 48 + i * 8 + srow;
            async16(Wb + (size_t)r * EMBED + k0 + ((sblk ^ (r & 7)) * 8),
                    &Blds[buf][(w * 48 + i * 8) * 64]);
        }
    };
    const float* abase = emb + (size_t)(row0 + sr) * EMBED + sg * 8;
    auto writeA = [&](int buf, float4 f0, float4 f1) {
        s16x8 v = { f2bf(f0.x), f2bf(f0.y), f2bf(f0.z), f2bf(f0.w),
                    f2bf(f1.x), f2bf(f1.y), f2bf(f1.z), f2bf(f1.w) };
        *(s16x8*)&Alds[buf][sr * 64 + ((sg ^ (sr & 7)) * 8)] = v;
    };

    // prologue: tile0 -> LDS buf0; tile1 -> regs (f0a,f1a)
    float4 f0a = *(const float4*)(abase);
    float4 f1a = *(const float4*)(abase + 4);
    stageB(0, 0);
    writeA(0, f0a, f1a);
    f0a = *(const float4*)(abase + 64);
    f1a = *(const float4*)(abase + 68);
    __syncthreads();

    int cur = 0;
    const int ar = wr * 16 + (lane & 15);
    const int ag = lane >> 4;
    float4 f0b = f0a, f1b = f1a;

    for (int t = 0; t < 16; ++t) {
        if (t < 14) {   // issue A(t+2) -> regs (~2 iterations in flight)
            f0b = *(const float4*)(abase + (size_t)(t + 2) * 64);
            f1b = *(const float4*)(abase + (size_t)(t + 2) * 64 + 4);
        }
        stageB(cur ^ 1, t + 1 < 16 ? t + 1 : 15);

        s16x8 a0 = *(const s16x8*)&Alds[cur][ar * 64 + (((ag    ) ^ (ar & 7)) * 8)];
        s16x8 a1 = *(const s16x8*)&Alds[cur][ar * 64 + (((ag + 4) ^ (ar & 7)) * 8)];
#pragma unroll
        for (int n = 0; n < 6; ++n) {
            int br = wc * 96 + n * 16 + (lane & 15);
            s16x8 b0 = *(const s16x8*)&Blds[cur][br * 64 + (((ag    ) ^ (br & 7)) * 8)];
            s16x8 b1 = *(const s16x8*)&Blds[cur][br * 64 + (((ag + 4) ^ (br & 7)) * 8)];
            acc[n] = __builtin_amdgcn_mfma_f32_16x16x32_bf16(a0, b0, acc[n], 0, 0, 0);
            acc[n] = __builtin_amdgcn_mfma_f32_16x16x32_bf16(a1, b1, acc[n], 0, 0, 0);
        }
        writeA(cur ^ 1, f0a, f1a);   // A(t+1) into the other buffer
        __syncthreads();
        f0a = f0b; f1a = f1b;
        cur ^= 1;
    }

    // epilogue: C layout col=lane&15, row=(lane>>4)*4+reg
    const int rbase = row0 + wr * 16 + ((lane >> 4) * 4);
    const int cl = lane & 15;
#pragma unroll
    for (int n = 0; n < 6; ++n) {
        int col = wc * 96 + n * 16 + cl;
        int mat = col >> 6;
        int c = col & 63;
#pragma unroll
        for (int r = 0; r < 4; ++r) {
            int row = rbase + r;
            int b = row >> 12, s = row & 4095;
            short v = f2bf(acc[n][r]);
            if (mat == 0)       Qb[((size_t)b * SEQ + s) * HD + c] = v;
            else if (mat == 1)  Kb[((size_t)b * SEQ + s) * HD + c] = v;
            else                Vt[((size_t)b * HD + c) * SEQ + s] = v;
        }
    }
}

// ---------------------------------------------------------------------------
// Kernel 2: causal flash attention — swapped QK^T, barrier-free, LDS-free.
// Block (jq,b,p): 4 independent waves x 16 q rows; kv tiles [p*CH, ...).
// Each lane owns ONE q (=lane&15); P^T B-frags assembled in-register with a
// packed 8-bpermute scheme: source lane (g',l15) exposes pk[2kk+(g'&1)][j]
// (then the complement), destination fetches from lane (2(g&1)+(g>>1))*16+l15
// (then complement) -> source parity == destination's needed block bit.
// ---------------------------------------------------------------------------
__global__ __launch_bounds__(256) void attn_fwd(
    const short* __restrict__ Qb, const short* __restrict__ Kb,
    const short* __restrict__ Vt, float* __restrict__ Op, float* __restrict__ Ml)
{
    const int jq = blockIdx.x;       // q-tile 0..63
    const int b  = blockIdx.y;
    const int p  = blockIdx.z;       // partition 0..7
    const int t0 = p * CH;
    if (t0 > jq) return;
    const int t1 = min(t0 + CH, jq + 1);

    const int tid  = threadIdx.x;
    const int lane = tid & 63;
    const int w    = tid >> 6;
    const int l15  = lane & 15;
    const int g    = lane >> 4;
    const int q0w  = jq * 64 + w * 16;     // this wave's q base

    const short* Kb_b = Kb + (size_t)b * SEQ * HD;
    const short* Vt_b = Vt + (size_t)b * HD * SEQ;

    // persistent Q B-frags: col=q=l15, k=d=g*8+e (+32)
    const short* qp = Qb + ((size_t)b * SEQ + q0w + l15) * HD + g * 8;
    s16x8 qb0 = *(const s16x8*)qp;
    s16x8 qb1 = *(const s16x8*)(qp + 32);

    f32x4 o[4];
#pragma unroll
    for (int n = 0; n < 4; ++n) o[n] = f32x4{0.f, 0.f, 0.f, 0.f};
    float m = -INFINITY, l = 0.f;

    // K A-frags: row=kv=n*16+l15, k=d=g*8+e (+32)
    s16x8 ka0[4], ka1[4];
    auto loadK = [&](int t) {
        const short* kp = Kb_b + ((size_t)t * 64 + l15) * HD + g * 8;
#pragma unroll
        for (int n = 0; n < 4; ++n) {
            ka0[n] = *(const s16x8*)(kp + n * 16 * HD);
            ka1[n] = *(const s16x8*)(kp + n * 16 * HD + 32);
        }
    };
    loadK(t0);

    // P^T shuffle: fetch lanes (loop-invariant)
    const int f1l = (2 * (g & 1) + (g >> 1)) * 16 + l15;
    const int f2l = (2 * (g & 1) + 1 - (g >> 1)) * 16 + l15;
    const bool podd = (g & 1) != 0;
    const bool hbit = (g >> 1) != 0;

    for (int t = t0; t < t1; ++t) {
        // S^T = K Q^T : st[n][r] = S^T[kv = n*16+g*4+r][q = l15]
        f32x4 st[4];
#pragma unroll
        for (int n = 0; n < 4; ++n) {
            st[n] = __builtin_amdgcn_mfma_f32_16x16x32_bf16(ka0[n], qb0, f32x4{0.f,0.f,0.f,0.f}, 0, 0, 0);
            st[n] = __builtin_amdgcn_mfma_f32_16x16x32_bf16(ka1[n], qb1, st[n], 0, 0, 0);
        }
        loadK(t + 1 < t1 ? t + 1 : t);   // prefetch next K while softmax runs

        // V^T A-frags for this tile: row=d=n*16+l15, k=kv=kk*32+g*8+e
        s16x8 va[4][2];
#pragma unroll
        for (int n = 0; n < 4; ++n)
#pragma unroll
            for (int kk = 0; kk < 2; ++kk)
                va[n][kk] = *(const s16x8*)(Vt_b + (size_t)(n * 16 + l15) * SEQ
                                            + (size_t)t * 64 + kk * 32 + g * 8);

        if (t == jq) {   // causal mask on diagonal tile
#pragma unroll
            for (int n = 0; n < 4; ++n)
#pragma unroll
                for (int r = 0; r < 4; ++r) {
                    int kvg = t * 64 + n * 16 + g * 4 + r;
                    if (kvg > q0w + l15) st[n][r] = -INFINITY;
                }
        }

        // row max for q=l15: in-lane 16 + xor16 + xor32
        float mt = fmaxf(fmaxf(st[0][0], st[0][1]), fmaxf(st[0][2], st[0][3]));
#pragma unroll
        for (int n = 1; n < 4; ++n)
            mt = fmaxf(mt, fmaxf(fmaxf(st[n][0], st[n][1]), fmaxf(st[n][2], st[n][3])));
        mt = fmaxf(mt, __shfl_xor(mt, 16, 64));
        mt = fmaxf(mt, __shfl_xor(mt, 32, 64));

        float mn  = fmaxf(m, mt);
        float fac = __expf(m - mn);
        m = mn;

        float rs = 0.f;
        unsigned pk[4][2];
#pragma unroll
        for (int n = 0; n < 4; ++n) {
            unsigned u0 = (unsigned)(unsigned short)f2bf(__expf(st[n][0] - m));
            unsigned u1 = (unsigned)(unsigned short)f2bf(__expf(st[n][1] - m));
            unsigned u2 = (unsigned)(unsigned short)f2bf(__expf(st[n][2] - m));
            unsigned u3 = (unsigned)(unsigned short)f2bf(__expf(st[n][3] - m));
            pk[n][0] = u0 | (u1 << 16);
            pk[n][1] = u2 | (u3 << 16);
            // accumulate the QUANTIZED p so numerator/denominator match
            rs += bf2f((short)u0) + bf2f((short)u1) + bf2f((short)u2) + bf2f((short)u3);
        }
        rs += __shfl_xor(rs, 16, 64);
        rs += __shfl_xor(rs, 32, 64);
        l = l * fac + rs;
#pragma unroll
        for (int n = 0; n < 4; ++n)
#pragma unroll
            for (int r = 0; r < 4; ++r) o[n][r] *= fac;

        // O^T += V^T P^T ; B-frag: col=q=l15, k=kv=kk*32+g*8+e
#pragma unroll
        for (int kk = 0; kk < 2; ++kk) {
            // expose (source side): pk[2kk + parity][j], then complement
            unsigned e00 = podd ? pk[2 * kk + 1][0] : pk[2 * kk][0];
            unsigned e01 = podd ? pk[2 * kk + 1][1] : pk[2 * kk][1];
            unsigned e10 = podd ? pk[2 * kk][0]     : pk[2 * kk + 1][0];
            unsigned e11 = podd ? pk[2 * kk][1]     : pk[2 * kk + 1][1];
            unsigned x0 = (unsigned)__shfl((int)e00, f1l, 64);
            unsigned x1 = (unsigned)__shfl((int)e01, f1l, 64);
            unsigned y0 = (unsigned)__shfl((int)e10, f2l, 64);
            unsigned y1 = (unsigned)__shfl((int)e11, f2l, 64);
            unsigned w0 = hbit ? y0 : x0;   // kv = kk*32+g*8 + {0,1}
            unsigned w1 = hbit ? y1 : x1;   //                + {2,3}
            unsigned w2 = hbit ? x0 : y0;   //                + {4,5}
            unsigned w3 = hbit ? x1 : y1;   //                + {6,7}
            u32x4 uu = { w0, w1, w2, w3 };
            s16x8 pb = __builtin_bit_cast(s16x8, uu);
#pragma unroll
            for (int n = 0; n < 4; ++n)
                o[n] = __builtin_amdgcn_mfma_f32_16x16x32_bf16(va[n][kk], pb, o[n], 0, 0, 0);
        }
    }

    // epilogue: O^T partial [d][q], coalesced 4x64B per store
    const size_t pidx = ((size_t)b * 64 + jq) * NP + p;
    float* opb = Op + pidx * 4096;
#pragma unroll
    for (int n = 0; n < 4; ++n)
#pragma unroll
        for (int r = 0; r < 4; ++r)
            opb[(n * 16 + g * 4 + r) * 64 + w * 16 + l15] = o[n][r];
    if (lane < 16) {
        float* mlb = Ml + pidx * 128;
        mlb[w * 16 + l15]      = m;
        mlb[64 + w * 16 + l15] = l;
    }
}

// ---------------------------------------------------------------------------
// Kernel 3: merge <=8 partials per (b, q-tile) -> normalized out[q][d] fp32
// ---------------------------------------------------------------------------
__global__ __launch_bounds__(256) void attn_combine(
    const float* __restrict__ Op, const float* __restrict__ Ml,
    float* __restrict__ out)
{
    const int jq = blockIdx.x;
    const int b  = blockIdx.y;
    const int nP = (jq >> 3) + 1;
    const int tid = threadIdx.x;
    const int q  = tid & 63;
    const int dc = tid >> 6;          // 0..3
    const size_t pb = ((size_t)b * 64 + jq) * NP;

    float mv[NP], lv[NP], wt[NP];
    float mstar = -INFINITY;
#pragma unroll
    for (int p = 0; p < NP; ++p) if (p < nP) {
        mv[p] = Ml[(pb + p) * 128 + q];
        lv[p] = Ml[(pb + p) * 128 + 64 + q];
        mstar = fmaxf(mstar, mv[p]);
    }
    float L = 0.f;
#pragma unroll
    for (int p = 0; p < NP; ++p) if (p < nP) {
        wt[p] = __expf(mv[p] - mstar);
        L += lv[p] * wt[p];
    }
    float inv = 1.0f / L;

    float acc[16];
#pragma unroll
    for (int k = 0; k < 16; ++k) acc[k] = 0.f;
#pragma unroll
    for (int p = 0; p < NP; ++p) if (p < nP) {
        const float* src = Op + (pb + p) * 4096 + (size_t)dc * 16 * 64 + q;
#pragma unroll
        for (int k = 0; k < 16; ++k) acc[k] += src[k * 64] * wt[p];
    }
    float* dst = out + ((size_t)b * SEQ + jq * 64 + q) * HD + dc * 16;
#pragma unroll
    for (int k = 0; k < 16; ++k) dst[k] = acc[k] * inv;
}

// ---------------------------------------------------------------------------
extern "C" void kernel_launch(void* const* d_in, const int* in_sizes, int n_in,
                              void* d_out, int out_size, void* d_ws, size_t ws_size,
                              hipStream_t stream)
{
    (void)in_sizes; (void)n_in; (void)out_size; (void)ws_size;
    const float* emb = (const float*)d_in[0];
    const float* wq  = (const float*)d_in[1];
    const float* wk  = (const float*)d_in[2];
    const float* wv  = (const float*)d_in[3];
    float* out = (float*)d_out;

    short* Wb = (short*)d_ws;                          // [192][1024] bf16
    short* Qb = Wb + 192 * 1024;                       // [4][4096][64] bf16
    short* Kb = Qb + (size_t)NBATCH * SEQ * HD;        // [4][4096][64] bf16
    short* Vt = Kb + (size_t)NBATCH * SEQ * HD;        // [4][64][4096] bf16
    float* Op = (float*)(Vt + (size_t)NBATCH * SEQ * HD);  // [4][64][8][64][64] f32 (O^T)
    float* Ml = Op + (size_t)NBATCH * 64 * NP * 64 * 64;   // [4][64][8][128] f32

    hipLaunchKernelGGL(prep_w, dim3(96), dim3(256), 0, stream, wq, wk, wv, Wb);
    hipLaunchKernelGGL(proj_qkv, dim3(512), dim3(256), 0, stream, emb, Wb, Qb, Kb, Vt);
    hipLaunchKernelGGL(attn_fwd, dim3(64, NBATCH, NP), dim3(256), 0, stream,
                       Qb, Kb, Vt, Op, Ml);
    hipLaunchKernelGGL(attn_combine, dim3(64, NBATCH), dim3(256), 0, stream,
                       Op, Ml, out);
}

// Round 5
// 154.669 us; speedup vs baseline: 1.4052x; 1.4052x over previous
//
#include <hip/hip_runtime.h>
#include <hip/hip_bf16.h>

#define EMBED 1024
#define SEQ   4096
#define NBATCH 4
#define HD    64
#define CH    8    // kv tiles (of 64) per attention partition
#define NP    8    // max partitions

typedef __attribute__((ext_vector_type(8))) short s16x8;
typedef __attribute__((ext_vector_type(4))) float f32x4;
typedef __attribute__((ext_vector_type(4))) unsigned int u32x4;

__device__ __forceinline__ short f2bf(float f) {
    unsigned u = __builtin_bit_cast(unsigned, f);
    u += 0x7fffu + ((u >> 16) & 1u);      // round-to-nearest-even
    return (short)(u >> 16);
}
__device__ __forceinline__ float bf2f(short h) {
    unsigned u = ((unsigned)(unsigned short)h) << 16;
    return __builtin_bit_cast(float, u);
}

typedef const unsigned int __attribute__((address_space(1)))* gbl_ptr_t;
typedef unsigned int __attribute__((address_space(3)))* lds_ptr_t;
__device__ __forceinline__ void async16(const void* g, void* l) {
    __builtin_amdgcn_global_load_lds((gbl_ptr_t)g, (lds_ptr_t)l, 16, 0, 0);
}

// ---------------------------------------------------------------------------
// Kernel 0: W_Q (pre-scaled by 1/8), W_K, W_V fp32 -> bf16 Wb[192][1024]
// ---------------------------------------------------------------------------
__global__ __launch_bounds__(256) void prep_w(
    const float* __restrict__ wq, const float* __restrict__ wk,
    const float* __restrict__ wv, short* __restrict__ Wb)
{
    int idx = blockIdx.x * 256 + threadIdx.x;
    int e = idx * 8;
    int row = e >> 10, col = e & 1023;
    const float* src = (row < 64) ? (wq + (size_t)row * EMBED)
                     : (row < 128) ? (wk + (size_t)(row - 64) * EMBED)
                                   : (wv + (size_t)(row - 128) * EMBED);
    float sc = (row < 64) ? 0.125f : 1.0f;
    float4 f0 = *(const float4*)(src + col);
    float4 f1 = *(const float4*)(src + col + 4);
    s16x8 v = { f2bf(f0.x*sc), f2bf(f0.y*sc), f2bf(f0.z*sc), f2bf(f0.w*sc),
                f2bf(f1.x*sc), f2bf(f1.y*sc), f2bf(f1.z*sc), f2bf(f1.w*sc) };
    *(s16x8*)&Wb[e] = v;
}

// ---------------------------------------------------------------------------
// Kernel 1: QKV projection. BM=64, BN=192, BK=64; 8 waves (4 row x 2 col),
// 256 blocks (all resident, 2 waves/SIMD). Depth-2 A-prefetch in regs,
// double-buffered LDS, B staged via global_load_lds from bf16 Wb.
// ---------------------------------------------------------------------------
__global__ __launch_bounds__(512) void proj_qkv(
    const float* __restrict__ emb, const short* __restrict__ Wb,
    short* __restrict__ Qb, short* __restrict__ Kb, short* __restrict__ Vt)
{
    __shared__ short Alds[2][64 * 64];    // 2 x 8 KB
    __shared__ short Blds[2][192 * 64];   // 2 x 24 KB

    const int tid  = threadIdx.x;
    const int lane = tid & 63;
    const int w    = tid >> 6;        // 0..7
    const int wr   = w & 3;           // row group (16 rows)
    const int wc   = w >> 2;          // col group (96 cols)
    const int row0 = blockIdx.x * 64;
    const int l15  = lane & 15;
    const int g    = lane >> 4;

    const int sr   = tid >> 3;        // A staging row 0..63
    const int sg   = tid & 7;         // A 16B group 0..7
    const int srow = lane >> 3;
    const int sblk = lane & 7;

    f32x4 acc[6];
#pragma unroll
    for (int i = 0; i < 6; ++i) acc[i] = f32x4{0.f, 0.f, 0.f, 0.f};

    auto stageB = [&](int buf, int t) {
        const int k0 = t * 64;
#pragma unroll
        for (int i = 0; i < 3; ++i) {
            int r = w * 24 + i * 8 + srow;
            async16(Wb + (size_t)r * EMBED + k0 + ((sblk ^ (r & 7)) * 8),
                    &Blds[buf][(w * 24 + i * 8) * 64]);
        }
    };
    const float* abase = emb + (size_t)(row0 + sr) * EMBED + sg * 8;
    auto writeA = [&](int buf, float4 f0, float4 f1) {
        s16x8 v = { f2bf(f0.x), f2bf(f0.y), f2bf(f0.z), f2bf(f0.w),
                    f2bf(f1.x), f2bf(f1.y), f2bf(f1.z), f2bf(f1.w) };
        *(s16x8*)&Alds[buf][sr * 64 + ((sg ^ (sr & 7)) * 8)] = v;
    };

    // prologue: tile0 -> LDS buf0; tile1 -> regs
    float4 f0a = *(const float4*)(abase);
    float4 f1a = *(const float4*)(abase + 4);
    stageB(0, 0);
    writeA(0, f0a, f1a);
    f0a = *(const float4*)(abase + 64);
    f1a = *(const float4*)(abase + 68);
    __syncthreads();

    int cur = 0;
    const int ar = wr * 16 + l15;
    float4 f0b = f0a, f1b = f1a;

    for (int t = 0; t < 16; ++t) {
        if (t < 14) {   // A(t+2) -> regs
            f0b = *(const float4*)(abase + (size_t)(t + 2) * 64);
            f1b = *(const float4*)(abase + (size_t)(t + 2) * 64 + 4);
        }
        if (t < 15) stageB(cur ^ 1, t + 1);

        s16x8 a0 = *(const s16x8*)&Alds[cur][ar * 64 + (((g    ) ^ (ar & 7)) * 8)];
        s16x8 a1 = *(const s16x8*)&Alds[cur][ar * 64 + (((g + 4) ^ (ar & 7)) * 8)];
#pragma unroll
        for (int n = 0; n < 6; ++n) {
            int br = wc * 96 + n * 16 + l15;
            s16x8 b0 = *(const s16x8*)&Blds[cur][br * 64 + (((g    ) ^ (br & 7)) * 8)];
            s16x8 b1 = *(const s16x8*)&Blds[cur][br * 64 + (((g + 4) ^ (br & 7)) * 8)];
            acc[n] = __builtin_amdgcn_mfma_f32_16x16x32_bf16(a0, b0, acc[n], 0, 0, 0);
            acc[n] = __builtin_amdgcn_mfma_f32_16x16x32_bf16(a1, b1, acc[n], 0, 0, 0);
        }
        if (t < 15) writeA(cur ^ 1, f0a, f1a);   // A(t+1) into other buffer
        __syncthreads();
        f0a = f0b; f1a = f1b;
        cur ^= 1;
    }

    // epilogue: C layout col=lane&15, row=(lane>>4)*4+reg
    const int rbase = row0 + wr * 16 + g * 4;
#pragma unroll
    for (int n = 0; n < 6; ++n) {
        int col = wc * 96 + n * 16 + l15;
        int mat = col >> 6;
        int c = col & 63;
#pragma unroll
        for (int r = 0; r < 4; ++r) {
            int row = rbase + r;
            int b = row >> 12, s = row & 4095;
            short v = f2bf(acc[n][r]);
            if (mat == 0)       Qb[((size_t)b * SEQ + s) * HD + c] = v;
            else if (mat == 1)  Kb[((size_t)b * SEQ + s) * HD + c] = v;
            else                Vt[((size_t)b * HD + c) * SEQ + s] = v;
        }
    }
}

// ---------------------------------------------------------------------------
// Kernel 2: causal flash attention. Coalesced double-buffered LDS staging
// (round-2, verified) + swapped-QK in-register softmax & 8-bpermute P^T
// assembly (round-4, verified). 40 KB LDS -> 4 blocks/CU. CH=8 partitions.
// ---------------------------------------------------------------------------
__global__ __launch_bounds__(256) void attn_fwd(
    const short* __restrict__ Qb, const short* __restrict__ Kb,
    const short* __restrict__ Vt, float* __restrict__ Op, float* __restrict__ Ml)
{
    const int jq = blockIdx.x;       // q-tile 0..63
    const int b  = blockIdx.y;
    const int p  = blockIdx.z;       // partition 0..7
    const int t0 = p * CH;
    if (t0 > jq) return;
    const int t1 = min(t0 + CH, jq + 1);

    __shared__ short Qlds[64 * 64];        // 8 KB [q][d] swizzled
    __shared__ short Klds[2][64 * 64];     // 16 KB [kv][d]
    __shared__ short Vlds[2][64 * 64];     // 16 KB [d][kv]

    const int tid  = threadIdx.x;
    const int lane = tid & 63;
    const int w    = tid >> 6;
    const int l15  = lane & 15;
    const int g    = lane >> 4;
    const int q0w  = jq * 64 + w * 16;

    const short* Qbase  = Qb + ((size_t)b * SEQ + jq * 64) * HD;
    const short* Kbase0 = Kb + (size_t)b * SEQ * HD;
    const short* Vbase0 = Vt + (size_t)b * HD * SEQ;

    const int srow = lane >> 3;
    const int sblk = lane & 7;

    auto stageKV = [&](int buf, int t) {
        const int kv0 = t * 64;
#pragma unroll
        for (int i = 0; i < 2; ++i) {
            int r = w * 16 + i * 8 + srow;
            async16(Kbase0 + (size_t)(kv0 + r) * HD + ((sblk ^ (r & 7)) * 8),
                    &Klds[buf][(w * 16 + i * 8) * 64]);
            async16(Vbase0 + (size_t)r * SEQ + kv0 + ((sblk ^ (r & 7)) * 8),
                    &Vlds[buf][(w * 16 + i * 8) * 64]);
        }
    };

    // prologue: Q tile + first K/V tile
#pragma unroll
    for (int i = 0; i < 2; ++i) {
        int r = w * 16 + i * 8 + srow;
        async16(Qbase + (size_t)r * HD + ((sblk ^ (r & 7)) * 8),
                &Qlds[(w * 16 + i * 8) * 64]);
    }
    stageKV(0, t0);
    __syncthreads();

    // persistent Q B-frags: col=q=l15 (of this wave's 16), k=d=g*8 (+32)
    const int qr = w * 16 + l15;
    s16x8 qb0 = *(const s16x8*)&Qlds[qr * 64 + (((g    ) ^ (qr & 7)) * 8)];
    s16x8 qb1 = *(const s16x8*)&Qlds[qr * 64 + (((g + 4) ^ (qr & 7)) * 8)];

    f32x4 o[4];
#pragma unroll
    for (int n = 0; n < 4; ++n) o[n] = f32x4{0.f, 0.f, 0.f, 0.f};
    float m = -INFINITY, l = 0.f;

    // P^T shuffle lanes (verified round 4)
    const int f1l = (2 * (g & 1) + (g >> 1)) * 16 + l15;
    const int f2l = (2 * (g & 1) + 1 - (g >> 1)) * 16 + l15;
    const bool podd = (g & 1) != 0;
    const bool hbit = (g >> 1) != 0;

    int cur = 0;
    for (int t = t0; t < t1; ++t) {
        if (t + 1 < t1) stageKV(cur ^ 1, t + 1);

        // S^T = K Q^T : st[n][r] = S^T[kv=n*16+g*4+r][q=l15]
        f32x4 st[4];
#pragma unroll
        for (int n = 0; n < 4; ++n) {
            int kr = n * 16 + l15;
            s16x8 ka0 = *(const s16x8*)&Klds[cur][kr * 64 + (((g    ) ^ (kr & 7)) * 8)];
            s16x8 ka1 = *(const s16x8*)&Klds[cur][kr * 64 + (((g + 4) ^ (kr & 7)) * 8)];
            st[n] = __builtin_amdgcn_mfma_f32_16x16x32_bf16(ka0, qb0, f32x4{0.f,0.f,0.f,0.f}, 0, 0, 0);
            st[n] = __builtin_amdgcn_mfma_f32_16x16x32_bf16(ka1, qb1, st[n], 0, 0, 0);
        }

        if (t == jq) {   // causal mask on diagonal tile
#pragma unroll
            for (int n = 0; n < 4; ++n)
#pragma unroll
                for (int r = 0; r < 4; ++r) {
                    int kvg = t * 64 + n * 16 + g * 4 + r;
                    if (kvg > q0w + l15) st[n][r] = -INFINITY;
                }
        }

        // row max for q=l15: in-lane 16 + xor16 + xor32
        float mt = fmaxf(fmaxf(st[0][0], st[0][1]), fmaxf(st[0][2], st[0][3]));
#pragma unroll
        for (int n = 1; n < 4; ++n)
            mt = fmaxf(mt, fmaxf(fmaxf(st[n][0], st[n][1]), fmaxf(st[n][2], st[n][3])));
        mt = fmaxf(mt, __shfl_xor(mt, 16, 64));
        mt = fmaxf(mt, __shfl_xor(mt, 32, 64));

        float mn  = fmaxf(m, mt);
        float fac = __expf(m - mn);
        m = mn;

        float rs = 0.f;
        unsigned pk[4][2];
#pragma unroll
        for (int n = 0; n < 4; ++n) {
            unsigned u0 = (unsigned)(unsigned short)f2bf(__expf(st[n][0] - m));
            unsigned u1 = (unsigned)(unsigned short)f2bf(__expf(st[n][1] - m));
            unsigned u2 = (unsigned)(unsigned short)f2bf(__expf(st[n][2] - m));
            unsigned u3 = (unsigned)(unsigned short)f2bf(__expf(st[n][3] - m));
            pk[n][0] = u0 | (u1 << 16);
            pk[n][1] = u2 | (u3 << 16);
            rs += bf2f((short)u0) + bf2f((short)u1) + bf2f((short)u2) + bf2f((short)u3);
        }
        rs += __shfl_xor(rs, 16, 64);
        rs += __shfl_xor(rs, 32, 64);
        l = l * fac + rs;
#pragma unroll
        for (int n = 0; n < 4; ++n)
#pragma unroll
            for (int r = 0; r < 4; ++r) o[n][r] *= fac;

        // O^T += V^T P^T ; P^T B-frag: col=q=l15, k=kv=kk*32+g*8+e
#pragma unroll
        for (int kk = 0; kk < 2; ++kk) {
            unsigned e00 = podd ? pk[2 * kk + 1][0] : pk[2 * kk][0];
            unsigned e01 = podd ? pk[2 * kk + 1][1] : pk[2 * kk][1];
            unsigned e10 = podd ? pk[2 * kk][0]     : pk[2 * kk + 1][0];
            unsigned e11 = podd ? pk[2 * kk][1]     : pk[2 * kk + 1][1];
            unsigned x0 = (unsigned)__shfl((int)e00, f1l, 64);
            unsigned x1 = (unsigned)__shfl((int)e01, f1l, 64);
            unsigned y0 = (unsigned)__shfl((int)e10, f2l, 64);
            unsigned y1 = (unsigned)__shfl((int)e11, f2l, 64);
            unsigned w0 = hbit ? y0 : x0;
            unsigned w1 = hbit ? y1 : x1;
            unsigned w2 = hbit ? x0 : y0;
            unsigned w3 = hbit ? x1 : y1;
            u32x4 uu = { w0, w1, w2, w3 };
            s16x8 pb = __builtin_bit_cast(s16x8, uu);
#pragma unroll
            for (int n = 0; n < 4; ++n) {
                int vr = n * 16 + l15;
                s16x8 va = *(const s16x8*)&Vlds[cur][vr * 64 + (((g + kk * 4) ^ (vr & 7)) * 8)];
                o[n] = __builtin_amdgcn_mfma_f32_16x16x32_bf16(va, pb, o[n], 0, 0, 0);
            }
        }
        __syncthreads();   // staged t+1 complete; all waves done with cur
        cur ^= 1;
    }

    // epilogue: O^T partial [d][q] (coalesced), plus (m,l)
    const size_t pidx = ((size_t)b * 64 + jq) * NP + p;
    float* opb = Op + pidx * 4096;
#pragma unroll
    for (int n = 0; n < 4; ++n)
#pragma unroll
        for (int r = 0; r < 4; ++r)
            opb[(n * 16 + g * 4 + r) * 64 + w * 16 + l15] = o[n][r];
    if (lane < 16) {
        float* mlb = Ml + pidx * 128;
        mlb[w * 16 + l15]      = m;
        mlb[64 + w * 16 + l15] = l;
    }
}

// ---------------------------------------------------------------------------
// Kernel 3: merge <=8 partials per (b, q-tile) -> normalized out[q][d] fp32
// ---------------------------------------------------------------------------
__global__ __launch_bounds__(256) void attn_combine(
    const float* __restrict__ Op, const float* __restrict__ Ml,
    float* __restrict__ out)
{
    const int jq = blockIdx.x;
    const int b  = blockIdx.y;
    const int nP = (jq >> 3) + 1;
    const int tid = threadIdx.x;
    const int q  = tid & 63;
    const int dc = tid >> 6;          // 0..3
    const size_t pb = ((size_t)b * 64 + jq) * NP;

    float mv[NP], lv[NP], wt[NP];
    float mstar = -INFINITY;
#pragma unroll
    for (int p = 0; p < NP; ++p) if (p < nP) {
        mv[p] = Ml[(pb + p) * 128 + q];
        lv[p] = Ml[(pb + p) * 128 + 64 + q];
        mstar = fmaxf(mstar, mv[p]);
    }
    float L = 0.f;
#pragma unroll
    for (int p = 0; p < NP; ++p) if (p < nP) {
        wt[p] = __expf(mv[p] - mstar);
        L += lv[p] * wt[p];
    }
    float inv = 1.0f / L;

    float acc[16];
#pragma unroll
    for (int k = 0; k < 16; ++k) acc[k] = 0.f;
#pragma unroll
    for (int p = 0; p < NP; ++p) if (p < nP) {
        const float* src = Op + (pb + p) * 4096 + (size_t)dc * 16 * 64 + q;
#pragma unroll
        for (int k = 0; k < 16; ++k) acc[k] += src[k * 64] * wt[p];
    }
    float* dst = out + ((size_t)b * SEQ + jq * 64 + q) * HD + dc * 16;
#pragma unroll
    for (int k = 0; k < 16; ++k) dst[k] = acc[k] * inv;
}

// ---------------------------------------------------------------------------
extern "C" void kernel_launch(void* const* d_in, const int* in_sizes, int n_in,
                              void* d_out, int out_size, void* d_ws, size_t ws_size,
                              hipStream_t stream)
{
    (void)in_sizes; (void)n_in; (void)out_size; (void)ws_size;
    const float* emb = (const float*)d_in[0];
    const float* wq  = (const float*)d_in[1];
    const float* wk  = (const float*)d_in[2];
    const float* wv  = (const float*)d_in[3];
    float* out = (float*)d_out;

    short* Wb = (short*)d_ws;                          // [192][1024] bf16
    short* Qb = Wb + 192 * 1024;                       // [4][4096][64] bf16
    short* Kb = Qb + (size_t)NBATCH * SEQ * HD;        // [4][4096][64] bf16
    short* Vt = Kb + (size_t)NBATCH * SEQ * HD;        // [4][64][4096] bf16
    float* Op = (float*)(Vt + (size_t)NBATCH * SEQ * HD);  // [4][64][8][64][64] f32 (O^T)
    float* Ml = Op + (size_t)NBATCH * 64 * NP * 64 * 64;   // [4][64][8][128] f32

    hipLaunchKernelGGL(prep_w, dim3(96), dim3(256), 0, stream, wq, wk, wv, Wb);
    hipLaunchKernelGGL(proj_qkv, dim3(256), dim3(512), 0, stream, emb, Wb, Qb, Kb, Vt);
    hipLaunchKernelGGL(attn_fwd, dim3(64, NBATCH, NP), dim3(256), 0, stream,
                       Qb, Kb, Vt, Op, Ml);
    hipLaunchKernelGGL(attn_combine, dim3(64, NBATCH), dim3(256), 0, stream,
                       Op, Ml, out);
}

// Round 6
// 150.692 us; speedup vs baseline: 1.4422x; 1.0264x over previous
//
#include <hip/hip_runtime.h>
#include <hip/hip_bf16.h>

#define EMBED 1024
#define SEQ   4096
#define NBATCH 4
#define HD    64
#define CH    8    // kv tiles (of 64) per attention partition
#define NP    8    // max partitions

typedef __attribute__((ext_vector_type(8))) short s16x8;
typedef __attribute__((ext_vector_type(4))) float f32x4;
typedef __attribute__((ext_vector_type(4))) unsigned int u32x4;

__device__ __forceinline__ short f2bf(float f) {
    unsigned u = __builtin_bit_cast(unsigned, f);
    u += 0x7fffu + ((u >> 16) & 1u);      // round-to-nearest-even
    return (short)(u >> 16);
}

typedef const unsigned int __attribute__((address_space(1)))* gbl_ptr_t;
typedef unsigned int __attribute__((address_space(3)))* lds_ptr_t;
__device__ __forceinline__ void async16(const void* g, void* l) {
    __builtin_amdgcn_global_load_lds((gbl_ptr_t)g, (lds_ptr_t)l, 16, 0, 0);
}

// ---------------------------------------------------------------------------
// Kernel 0: W_Q (pre-scaled by 1/8), W_K, W_V fp32 -> bf16 Wb[192][1024]
// ---------------------------------------------------------------------------
__global__ __launch_bounds__(256) void prep_w(
    const float* __restrict__ wq, const float* __restrict__ wk,
    const float* __restrict__ wv, short* __restrict__ Wb)
{
    int idx = blockIdx.x * 256 + threadIdx.x;
    int e = idx * 8;
    int row = e >> 10, col = e & 1023;
    const float* src = (row < 64) ? (wq + (size_t)row * EMBED)
                     : (row < 128) ? (wk + (size_t)(row - 64) * EMBED)
                                   : (wv + (size_t)(row - 128) * EMBED);
    float sc = (row < 64) ? 0.125f : 1.0f;
    float4 f0 = *(const float4*)(src + col);
    float4 f1 = *(const float4*)(src + col + 4);
    s16x8 v = { f2bf(f0.x*sc), f2bf(f0.y*sc), f2bf(f0.z*sc), f2bf(f0.w*sc),
                f2bf(f1.x*sc), f2bf(f1.y*sc), f2bf(f1.z*sc), f2bf(f1.w*sc) };
    *(s16x8*)&Wb[e] = v;
}

// ---------------------------------------------------------------------------
// Kernel 1: QKV projection. BM=32, BN=192, BK=64; 512 blocks x 4 waves
// (2 blocks/CU -> independent barrier domains). Depth-2 A-prefetch in regs,
// double-buffered LDS, B staged via global_load_lds from bf16 Wb.
// ---------------------------------------------------------------------------
__global__ __launch_bounds__(256) void proj_qkv(
    const float* __restrict__ emb, const short* __restrict__ Wb,
    short* __restrict__ Qb, short* __restrict__ Kb, short* __restrict__ Vt)
{
    __shared__ short Alds[2][32 * 64];    // 2 x 4 KB
    __shared__ short Blds[2][192 * 64];   // 2 x 24 KB

    const int tid  = threadIdx.x;
    const int lane = tid & 63;
    const int w    = tid >> 6;
    const int wr   = w & 1;
    const int wc   = w >> 1;
    const int row0 = blockIdx.x * 32;

    const int sr   = tid >> 3;     // staging row 0..31
    const int sg   = tid & 7;      // 16B group 0..7
    const int srow = lane >> 3;
    const int sblk = lane & 7;

    f32x4 acc[6];
#pragma unroll
    for (int i = 0; i < 6; ++i) acc[i] = f32x4{0.f, 0.f, 0.f, 0.f};

    auto stageB = [&](int buf, int t) {
        const int k0 = t * 64;
#pragma unroll
        for (int i = 0; i < 6; ++i) {
            int r = w * 48 + i * 8 + srow;
            async16(Wb + (size_t)r * EMBED + k0 + ((sblk ^ (r & 7)) * 8),
                    &Blds[buf][(w * 48 + i * 8) * 64]);
        }
    };
    const float* abase = emb + (size_t)(row0 + sr) * EMBED + sg * 8;
    auto writeA = [&](int buf, float4 f0, float4 f1) {
        s16x8 v = { f2bf(f0.x), f2bf(f0.y), f2bf(f0.z), f2bf(f0.w),
                    f2bf(f1.x), f2bf(f1.y), f2bf(f1.z), f2bf(f1.w) };
        *(s16x8*)&Alds[buf][sr * 64 + ((sg ^ (sr & 7)) * 8)] = v;
    };

    // prologue: tile0 -> LDS buf0; tile1 -> regs
    float4 f0a = *(const float4*)(abase);
    float4 f1a = *(const float4*)(abase + 4);
    stageB(0, 0);
    writeA(0, f0a, f1a);
    f0a = *(const float4*)(abase + 64);
    f1a = *(const float4*)(abase + 68);
    __syncthreads();

    int cur = 0;
    const int ar = wr * 16 + (lane & 15);
    const int ag = lane >> 4;
    float4 f0b = f0a, f1b = f1a;

    for (int t = 0; t < 16; ++t) {
        if (t < 14) {   // A(t+2) -> regs
            f0b = *(const float4*)(abase + (size_t)(t + 2) * 64);
            f1b = *(const float4*)(abase + (size_t)(t + 2) * 64 + 4);
        }
        if (t < 15) stageB(cur ^ 1, t + 1);

        s16x8 a0 = *(const s16x8*)&Alds[cur][ar * 64 + (((ag    ) ^ (ar & 7)) * 8)];
        s16x8 a1 = *(const s16x8*)&Alds[cur][ar * 64 + (((ag + 4) ^ (ar & 7)) * 8)];
#pragma unroll
        for (int n = 0; n < 6; ++n) {
            int br = wc * 96 + n * 16 + (lane & 15);
            s16x8 b0 = *(const s16x8*)&Blds[cur][br * 64 + (((ag    ) ^ (br & 7)) * 8)];
            s16x8 b1 = *(const s16x8*)&Blds[cur][br * 64 + (((ag + 4) ^ (br & 7)) * 8)];
            acc[n] = __builtin_amdgcn_mfma_f32_16x16x32_bf16(a0, b0, acc[n], 0, 0, 0);
            acc[n] = __builtin_amdgcn_mfma_f32_16x16x32_bf16(a1, b1, acc[n], 0, 0, 0);
        }
        if (t < 15) writeA(cur ^ 1, f0a, f1a);
        __syncthreads();
        f0a = f0b; f1a = f1b;
        cur ^= 1;
    }

    // epilogue: C layout col=lane&15, row=(lane>>4)*4+reg
    const int rbase = row0 + wr * 16 + ((lane >> 4) * 4);
    const int cl = lane & 15;
#pragma unroll
    for (int n = 0; n < 6; ++n) {
        int col = wc * 96 + n * 16 + cl;
        int mat = col >> 6;
        int c = col & 63;
#pragma unroll
        for (int r = 0; r < 4; ++r) {
            int row = rbase + r;
            int b = row >> 12, s = row & 4095;
            short v = f2bf(acc[n][r]);
            if (mat == 0)       Qb[((size_t)b * SEQ + s) * HD + c] = v;
            else if (mat == 1)  Kb[((size_t)b * SEQ + s) * HD + c] = v;
            else                Vt[((size_t)b * HD + c) * SEQ + s] = v;
        }
    }
}

// ---------------------------------------------------------------------------
// Kernel 2: causal flash attention. Coalesced double-buffered LDS staging +
// swapped-QK in-register softmax + 8-bpermute P^T (verified r4/r5). New:
// longest-chains-first launch order, cvt_pk packing, defer-rescale (THR=8),
// setprio around MFMA, unquantized denominator.
// ---------------------------------------------------------------------------
__global__ __launch_bounds__(256) void attn_fwd(
    const short* __restrict__ Qb, const short* __restrict__ Kb,
    const short* __restrict__ Vt, float* __restrict__ Op, float* __restrict__ Ml)
{
    const int jq = 63 - blockIdx.x;  // q-tile, longest chains launch first
    const int b  = blockIdx.z;
    const int p  = blockIdx.y;       // partition 0..7
    const int t0 = p * CH;
    if (t0 > jq) return;
    const int t1 = min(t0 + CH, jq + 1);

    __shared__ short Qlds[64 * 64];        // 8 KB [q][d] swizzled
    __shared__ short Klds[2][64 * 64];     // 16 KB [kv][d]
    __shared__ short Vlds[2][64 * 64];     // 16 KB [d][kv]

    const int tid  = threadIdx.x;
    const int lane = tid & 63;
    const int w    = tid >> 6;
    const int l15  = lane & 15;
    const int g    = lane >> 4;
    const int q0w  = jq * 64 + w * 16;

    const short* Qbase  = Qb + ((size_t)b * SEQ + jq * 64) * HD;
    const short* Kbase0 = Kb + (size_t)b * SEQ * HD;
    const short* Vbase0 = Vt + (size_t)b * HD * SEQ;

    const int srow = lane >> 3;
    const int sblk = lane & 7;

    auto stageKV = [&](int buf, int t) {
        const int kv0 = t * 64;
#pragma unroll
        for (int i = 0; i < 2; ++i) {
            int r = w * 16 + i * 8 + srow;
            async16(Kbase0 + (size_t)(kv0 + r) * HD + ((sblk ^ (r & 7)) * 8),
                    &Klds[buf][(w * 16 + i * 8) * 64]);
            async16(Vbase0 + (size_t)r * SEQ + kv0 + ((sblk ^ (r & 7)) * 8),
                    &Vlds[buf][(w * 16 + i * 8) * 64]);
        }
    };

    // prologue: Q tile + first K/V tile
#pragma unroll
    for (int i = 0; i < 2; ++i) {
        int r = w * 16 + i * 8 + srow;
        async16(Qbase + (size_t)r * HD + ((sblk ^ (r & 7)) * 8),
                &Qlds[(w * 16 + i * 8) * 64]);
    }
    stageKV(0, t0);
    __syncthreads();

    // persistent Q B-frags: col=q=l15 (of this wave's 16), k=d=g*8 (+32)
    const int qr = w * 16 + l15;
    s16x8 qb0 = *(const s16x8*)&Qlds[qr * 64 + (((g    ) ^ (qr & 7)) * 8)];
    s16x8 qb1 = *(const s16x8*)&Qlds[qr * 64 + (((g + 4) ^ (qr & 7)) * 8)];

    f32x4 o[4];
#pragma unroll
    for (int n = 0; n < 4; ++n) o[n] = f32x4{0.f, 0.f, 0.f, 0.f};
    float m = -INFINITY, l = 0.f;

    // P^T shuffle lanes (verified round 4)
    const int f1l = (2 * (g & 1) + (g >> 1)) * 16 + l15;
    const int f2l = (2 * (g & 1) + 1 - (g >> 1)) * 16 + l15;
    const bool podd = (g & 1) != 0;
    const bool hbit = (g >> 1) != 0;

    int cur = 0;
    for (int t = t0; t < t1; ++t) {
        if (t + 1 < t1) stageKV(cur ^ 1, t + 1);

        // S^T = K Q^T : st[n][r] = S^T[kv=n*16+g*4+r][q=l15]
        f32x4 st[4];
        __builtin_amdgcn_s_setprio(1);
#pragma unroll
        for (int n = 0; n < 4; ++n) {
            int kr = n * 16 + l15;
            s16x8 ka0 = *(const s16x8*)&Klds[cur][kr * 64 + (((g    ) ^ (kr & 7)) * 8)];
            s16x8 ka1 = *(const s16x8*)&Klds[cur][kr * 64 + (((g + 4) ^ (kr & 7)) * 8)];
            st[n] = __builtin_amdgcn_mfma_f32_16x16x32_bf16(ka0, qb0, f32x4{0.f,0.f,0.f,0.f}, 0, 0, 0);
            st[n] = __builtin_amdgcn_mfma_f32_16x16x32_bf16(ka1, qb1, st[n], 0, 0, 0);
        }
        __builtin_amdgcn_s_setprio(0);

        if (t == jq) {   // causal mask on diagonal tile
#pragma unroll
            for (int n = 0; n < 4; ++n)
#pragma unroll
                for (int r = 0; r < 4; ++r) {
                    int kvg = t * 64 + n * 16 + g * 4 + r;
                    if (kvg > q0w + l15) st[n][r] = -INFINITY;
                }
        }

        // row max for q=l15: in-lane 16 + xor16 + xor32
        float mt = fmaxf(fmaxf(st[0][0], st[0][1]), fmaxf(st[0][2], st[0][3]));
#pragma unroll
        for (int n = 1; n < 4; ++n)
            mt = fmaxf(mt, fmaxf(fmaxf(st[n][0], st[n][1]), fmaxf(st[n][2], st[n][3])));
        mt = fmaxf(mt, __shfl_xor(mt, 16, 64));
        mt = fmaxf(mt, __shfl_xor(mt, 32, 64));

        // defer-rescale (T13): only rescale when max grew by > 8
        if (__any(mt - m > 8.f)) {
            float mn  = fmaxf(m, mt);
            float fac = __expf(m - mn);
            m = mn;
            l *= fac;
#pragma unroll
            for (int n = 0; n < 4; ++n)
#pragma unroll
                for (int r = 0; r < 4; ++r) o[n][r] *= fac;
        }

        // P = exp(S^T - m), pack to bf16 via v_cvt_pk, f32 denominator
        float rs = 0.f;
        unsigned pk[4][2];
#pragma unroll
        for (int n = 0; n < 4; ++n) {
            float p0 = __expf(st[n][0] - m);
            float p1 = __expf(st[n][1] - m);
            float p2 = __expf(st[n][2] - m);
            float p3 = __expf(st[n][3] - m);
            rs += (p0 + p1) + (p2 + p3);
            asm("v_cvt_pk_bf16_f32 %0, %1, %2" : "=v"(pk[n][0]) : "v"(p0), "v"(p1));
            asm("v_cvt_pk_bf16_f32 %0, %1, %2" : "=v"(pk[n][1]) : "v"(p2), "v"(p3));
        }
        rs += __shfl_xor(rs, 16, 64);
        rs += __shfl_xor(rs, 32, 64);
        l += rs;

        // O^T += V^T P^T ; P^T B-frag: col=q=l15, k=kv=kk*32+g*8+e
        __builtin_amdgcn_s_setprio(1);
#pragma unroll
        for (int kk = 0; kk < 2; ++kk) {
            unsigned e00 = podd ? pk[2 * kk + 1][0] : pk[2 * kk][0];
            unsigned e01 = podd ? pk[2 * kk + 1][1] : pk[2 * kk][1];
            unsigned e10 = podd ? pk[2 * kk][0]     : pk[2 * kk + 1][0];
            unsigned e11 = podd ? pk[2 * kk][1]     : pk[2 * kk + 1][1];
            unsigned x0 = (unsigned)__shfl((int)e00, f1l, 64);
            unsigned x1 = (unsigned)__shfl((int)e01, f1l, 64);
            unsigned y0 = (unsigned)__shfl((int)e10, f2l, 64);
            unsigned y1 = (unsigned)__shfl((int)e11, f2l, 64);
            unsigned w0 = hbit ? y0 : x0;
            unsigned w1 = hbit ? y1 : x1;
            unsigned w2 = hbit ? x0 : y0;
            unsigned w3 = hbit ? x1 : y1;
            u32x4 uu = { w0, w1, w2, w3 };
            s16x8 pb = __builtin_bit_cast(s16x8, uu);
#pragma unroll
            for (int n = 0; n < 4; ++n) {
                int vr = n * 16 + l15;
                s16x8 va = *(const s16x8*)&Vlds[cur][vr * 64 + (((g + kk * 4) ^ (vr & 7)) * 8)];
                o[n] = __builtin_amdgcn_mfma_f32_16x16x32_bf16(va, pb, o[n], 0, 0, 0);
            }
        }
        __builtin_amdgcn_s_setprio(0);
        __syncthreads();   // staged t+1 complete; all waves done with cur
        cur ^= 1;
    }

    // epilogue: O^T partial [d][q] (coalesced), plus (m,l)
    const size_t pidx = ((size_t)b * 64 + jq) * NP + p;
    float* opb = Op + pidx * 4096;
#pragma unroll
    for (int n = 0; n < 4; ++n)
#pragma unroll
        for (int r = 0; r < 4; ++r)
            opb[(n * 16 + g * 4 + r) * 64 + w * 16 + l15] = o[n][r];
    if (lane < 16) {
        float* mlb = Ml + pidx * 128;
        mlb[w * 16 + l15]      = m;
        mlb[64 + w * 16 + l15] = l;
    }
}

// ---------------------------------------------------------------------------
// Kernel 3: merge <=8 partials per (b, q-tile) -> normalized out[q][d] fp32
// ---------------------------------------------------------------------------
__global__ __launch_bounds__(256) void attn_combine(
    const float* __restrict__ Op, const float* __restrict__ Ml,
    float* __restrict__ out)
{
    const int jq = blockIdx.x;
    const int b  = blockIdx.y;
    const int nP = (jq >> 3) + 1;
    const int tid = threadIdx.x;
    const int q  = tid & 63;
    const int dc = tid >> 6;          // 0..3
    const size_t pb = ((size_t)b * 64 + jq) * NP;

    float mv[NP], lv[NP], wt[NP];
    float mstar = -INFINITY;
#pragma unroll
    for (int p = 0; p < NP; ++p) if (p < nP) {
        mv[p] = Ml[(pb + p) * 128 + q];
        lv[p] = Ml[(pb + p) * 128 + 64 + q];
        mstar = fmaxf(mstar, mv[p]);
    }
    float L = 0.f;
#pragma unroll
    for (int p = 0; p < NP; ++p) if (p < nP) {
        wt[p] = __expf(mv[p] - mstar);
        L += lv[p] * wt[p];
    }
    float inv = 1.0f / L;

    float acc[16];
#pragma unroll
    for (int k = 0; k < 16; ++k) acc[k] = 0.f;
#pragma unroll
    for (int p = 0; p < NP; ++p) if (p < nP) {
        const float* src = Op + (pb + p) * 4096 + (size_t)dc * 16 * 64 + q;
#pragma unroll
        for (int k = 0; k < 16; ++k) acc[k] += src[k * 64] * wt[p];
    }
    float* dst = out + ((size_t)b * SEQ + jq * 64 + q) * HD + dc * 16;
#pragma unroll
    for (int k = 0; k < 16; ++k) dst[k] = acc[k] * inv;
}

// ---------------------------------------------------------------------------
extern "C" void kernel_launch(void* const* d_in, const int* in_sizes, int n_in,
                              void* d_out, int out_size, void* d_ws, size_t ws_size,
                              hipStream_t stream)
{
    (void)in_sizes; (void)n_in; (void)out_size; (void)ws_size;
    const float* emb = (const float*)d_in[0];
    const float* wq  = (const float*)d_in[1];
    const float* wk  = (const float*)d_in[2];
    const float* wv  = (const float*)d_in[3];
    float* out = (float*)d_out;

    short* Wb = (short*)d_ws;                          // [192][1024] bf16
    short* Qb = Wb + 192 * 1024;                       // [4][4096][64] bf16
    short* Kb = Qb + (size_t)NBATCH * SEQ * HD;        // [4][4096][64] bf16
    short* Vt = Kb + (size_t)NBATCH * SEQ * HD;        // [4][64][4096] bf16
    float* Op = (float*)(Vt + (size_t)NBATCH * SEQ * HD);  // [4][64][8][64][64] f32 (O^T)
    float* Ml = Op + (size_t)NBATCH * 64 * NP * 64 * 64;   // [4][64][8][128] f32

    hipLaunchKernelGGL(prep_w, dim3(96), dim3(256), 0, stream, wq, wk, wv, Wb);
    hipLaunchKernelGGL(proj_qkv, dim3(512), dim3(256), 0, stream, emb, Wb, Qb, Kb, Vt);
    hipLaunchKernelGGL(attn_fwd, dim3(64, NP, NBATCH), dim3(256), 0, stream,
                       Qb, Kb, Vt, Op, Ml);
    hipLaunchKernelGGL(attn_combine, dim3(64, NBATCH), dim3(256), 0, stream,
                       Op, Ml, out);
}

// Round 7
// 150.303 us; speedup vs baseline: 1.4460x; 1.0026x over previous
//
#include <hip/hip_runtime.h>
#include <hip/hip_bf16.h>

#define EMBED 1024
#define SEQ   4096
#define NBATCH 4
#define HD    64
#define CH    8    // kv tiles (of 64) per attention partition
#define NP    8    // max partitions (stride in partial buffers)

typedef __attribute__((ext_vector_type(8))) short s16x8;
typedef __attribute__((ext_vector_type(4))) float f32x4;
typedef __attribute__((ext_vector_type(4))) unsigned int u32x4;

__device__ __forceinline__ short f2bf(float f) {
    unsigned u = __builtin_bit_cast(unsigned, f);
    u += 0x7fffu + ((u >> 16) & 1u);      // round-to-nearest-even
    return (short)(u >> 16);
}

typedef const unsigned int __attribute__((address_space(1)))* gbl_ptr_t;
typedef unsigned int __attribute__((address_space(3)))* lds_ptr_t;
__device__ __forceinline__ void async16(const void* g, void* l) {
    __builtin_amdgcn_global_load_lds((gbl_ptr_t)g, (lds_ptr_t)l, 16, 0, 0);
}

// ---------------------------------------------------------------------------
// Kernel 0: W_Q (pre-scaled by 1/8), W_K, W_V fp32 -> bf16 Wb[192][1024]
// ---------------------------------------------------------------------------
__global__ __launch_bounds__(256) void prep_w(
    const float* __restrict__ wq, const float* __restrict__ wk,
    const float* __restrict__ wv, short* __restrict__ Wb)
{
    int idx = blockIdx.x * 256 + threadIdx.x;
    int e = idx * 8;
    int row = e >> 10, col = e & 1023;
    const float* src = (row < 64) ? (wq + (size_t)row * EMBED)
                     : (row < 128) ? (wk + (size_t)(row - 64) * EMBED)
                                   : (wv + (size_t)(row - 128) * EMBED);
    float sc = (row < 64) ? 0.125f : 1.0f;
    float4 f0 = *(const float4*)(src + col);
    float4 f1 = *(const float4*)(src + col + 4);
    s16x8 v = { f2bf(f0.x*sc), f2bf(f0.y*sc), f2bf(f0.z*sc), f2bf(f0.w*sc),
                f2bf(f1.x*sc), f2bf(f1.y*sc), f2bf(f1.z*sc), f2bf(f1.w*sc) };
    *(s16x8*)&Wb[e] = v;
}

// ---------------------------------------------------------------------------
// Kernel 1: QKV projection. BM=32, BN=192, BK=64; 512 blocks x 4 waves.
// Counted-vmcnt pipeline (T4): raw s_barrier, loads stay in flight across
// barriers. Per-wave per tile: B stage = 6 async16, A prefetch = 2 reg loads.
// ---------------------------------------------------------------------------
__global__ __launch_bounds__(256) void proj_qkv(
    const float* __restrict__ emb, const short* __restrict__ Wb,
    short* __restrict__ Qb, short* __restrict__ Kb, short* __restrict__ Vt)
{
    __shared__ short Alds[2][32 * 64];    // 2 x 4 KB
    __shared__ short Blds[2][192 * 64];   // 2 x 24 KB

    const int tid  = threadIdx.x;
    const int lane = tid & 63;
    const int w    = tid >> 6;
    const int wr   = w & 1;
    const int wc   = w >> 1;
    const int row0 = blockIdx.x * 32;

    const int sr   = tid >> 3;     // staging row 0..31
    const int sg   = tid & 7;      // 16B group 0..7
    const int srow = lane >> 3;
    const int sblk = lane & 7;

    f32x4 acc[6];
#pragma unroll
    for (int i = 0; i < 6; ++i) acc[i] = f32x4{0.f, 0.f, 0.f, 0.f};

    auto stageB = [&](int buf, int t) {
        const int k0 = t * 64;
#pragma unroll
        for (int i = 0; i < 6; ++i) {
            int r = w * 48 + i * 8 + srow;
            async16(Wb + (size_t)r * EMBED + k0 + ((sblk ^ (r & 7)) * 8),
                    &Blds[buf][(w * 48 + i * 8) * 64]);
        }
    };
    const float* abase = emb + (size_t)(row0 + sr) * EMBED + sg * 8;
    auto writeA = [&](int buf, float4 f0, float4 f1) {
        s16x8 v = { f2bf(f0.x), f2bf(f0.y), f2bf(f0.z), f2bf(f0.w),
                    f2bf(f1.x), f2bf(f1.y), f2bf(f1.z), f2bf(f1.w) };
        *(s16x8*)&Alds[buf][sr * 64 + ((sg ^ (sr & 7)) * 8)] = v;
    };

    // prologue: A(0)->regs, B(0) stage, A(0)->LDS, A(1)->regs, B(1) stage
    float4 f0a = *(const float4*)(abase);
    float4 f1a = *(const float4*)(abase + 4);
    stageB(0, 0);                     // 6 async16
    writeA(0, f0a, f1a);              // dep-waits A(0)
    f0a = *(const float4*)(abase + 64);
    f1a = *(const float4*)(abase + 68);
    stageB(1, 1);                     // outstanding: B0(6)+A1(2)+B1(6)
    asm volatile("s_waitcnt vmcnt(8) lgkmcnt(0)" ::: "memory");  // B0 done
    __builtin_amdgcn_s_barrier();
    __builtin_amdgcn_sched_barrier(0);

    int cur = 0;
    const int ar = wr * 16 + (lane & 15);
    const int ag = lane >> 4;

    for (int t = 0; t < 16; ++t) {
        // compute on buf cur
        s16x8 a0 = *(const s16x8*)&Alds[cur][ar * 64 + (((ag    ) ^ (ar & 7)) * 8)];
        s16x8 a1 = *(const s16x8*)&Alds[cur][ar * 64 + (((ag + 4) ^ (ar & 7)) * 8)];
#pragma unroll
        for (int n = 0; n < 6; ++n) {
            int br = wc * 96 + n * 16 + (lane & 15);
            s16x8 b0 = *(const s16x8*)&Blds[cur][br * 64 + (((ag    ) ^ (br & 7)) * 8)];
            s16x8 b1 = *(const s16x8*)&Blds[cur][br * 64 + (((ag + 4) ^ (br & 7)) * 8)];
            acc[n] = __builtin_amdgcn_mfma_f32_16x16x32_bf16(a0, b0, acc[n], 0, 0, 0);
            acc[n] = __builtin_amdgcn_mfma_f32_16x16x32_bf16(a1, b1, acc[n], 0, 0, 0);
        }
        if (t == 15) break;

        __builtin_amdgcn_s_barrier();          // all waves done reading cur
        __builtin_amdgcn_sched_barrier(0);
        writeA(cur ^ 1, f0a, f1a);             // A(t+1) -> nxt (dep-waits regs)
        if (t < 14) {
            f0a = *(const float4*)(abase + (size_t)(t + 2) * 64);
            f1a = *(const float4*)(abase + (size_t)(t + 2) * 64 + 4);
            stageB(cur, t + 2);                // B(t+2) -> cur (safe: barrier above)
            asm volatile("s_waitcnt vmcnt(8) lgkmcnt(0)" ::: "memory"); // B(t+1) done
        } else {
            asm volatile("s_waitcnt vmcnt(0) lgkmcnt(0)" ::: "memory");
        }
        __builtin_amdgcn_s_barrier();
        __builtin_amdgcn_sched_barrier(0);
        cur ^= 1;
    }

    // epilogue: C layout col=lane&15, row=(lane>>4)*4+reg
    const int rbase = row0 + wr * 16 + ((lane >> 4) * 4);
    const int cl = lane & 15;
#pragma unroll
    for (int n = 0; n < 6; ++n) {
        int col = wc * 96 + n * 16 + cl;
        int mat = col >> 6;
        int c = col & 63;
#pragma unroll
        for (int r = 0; r < 4; ++r) {
            int row = rbase + r;
            int b = row >> 12, s = row & 4095;
            short v = f2bf(acc[n][r]);
            if (mat == 0)       Qb[((size_t)b * SEQ + s) * HD + c] = v;
            else if (mat == 1)  Kb[((size_t)b * SEQ + s) * HD + c] = v;
            else                Vt[((size_t)b * HD + c) * SEQ + s] = v;
        }
    }
}

// ---------------------------------------------------------------------------
// Kernel 2: causal flash attention. Exact active grid (288 (jq,p) pairs per
// batch, longest-first), counted-vmcnt double-buffered staging, Q direct
// from global, swapped-QK in-register softmax + 8-bpermute P^T (verified).
// ---------------------------------------------------------------------------
__global__ __launch_bounds__(256) void attn_fwd(
    const short* __restrict__ Qb, const short* __restrict__ Kb,
    const short* __restrict__ Vt, float* __restrict__ Op, float* __restrict__ Ml)
{
    const int b = blockIdx.y;
    // invert triangular-band index: i in [0,288), descending work order
    const int i = 287 - blockIdx.x;
    int k = (int)((sqrtf((float)(16 + 16 * i)) - 4.0f) * 0.125f);
    while (4 * (k + 1) * (k + 2) <= i) ++k;
    while (4 * k * (k + 1) > i) --k;
    const int rem = i - 4 * k * (k + 1);
    const int kp1 = k + 1;
    const int jq = 8 * k + rem / kp1;       // q-tile
    const int p  = rem - (rem / kp1) * kp1; // partition 0..k
    const int t0 = p * CH;
    const int t1 = min(t0 + CH, jq + 1);

    __shared__ short Klds[2][64 * 64];     // 16 KB [kv][d] swizzled
    __shared__ short Vlds[2][64 * 64];     // 16 KB [d][kv] swizzled

    const int tid  = threadIdx.x;
    const int lane = tid & 63;
    const int w    = tid >> 6;
    const int l15  = lane & 15;
    const int g    = lane >> 4;
    const int q0w  = jq * 64 + w * 16;

    const short* Kbase0 = Kb + (size_t)b * SEQ * HD;
    const short* Vbase0 = Vt + (size_t)b * HD * SEQ;

    const int srow = lane >> 3;
    const int sblk = lane & 7;

    auto stageKV = [&](int buf, int t) {   // 4 async16 per wave
        const int kv0 = t * 64;
#pragma unroll
        for (int i2 = 0; i2 < 2; ++i2) {
            int r = w * 16 + i2 * 8 + srow;
            async16(Kbase0 + (size_t)(kv0 + r) * HD + ((sblk ^ (r & 7)) * 8),
                    &Klds[buf][(w * 16 + i2 * 8) * 64]);
            async16(Vbase0 + (size_t)r * SEQ + kv0 + ((sblk ^ (r & 7)) * 8),
                    &Vlds[buf][(w * 16 + i2 * 8) * 64]);
        }
    };

    // Q B-frags direct from global (coalesced 2KB/wave, r4-verified)
    const short* qp = Qb + ((size_t)b * SEQ + q0w + l15) * HD + g * 8;
    s16x8 qb0 = *(const s16x8*)qp;
    s16x8 qb1 = *(const s16x8*)(qp + 32);

    stageKV(0, t0);
    if (t0 + 1 < t1) {
        stageKV(1, t0 + 1);
        asm volatile("s_waitcnt vmcnt(4)" ::: "memory");  // buf0 ready
    } else {
        asm volatile("s_waitcnt vmcnt(0)" ::: "memory");
    }
    __builtin_amdgcn_s_barrier();
    __builtin_amdgcn_sched_barrier(0);

    f32x4 o[4];
#pragma unroll
    for (int n = 0; n < 4; ++n) o[n] = f32x4{0.f, 0.f, 0.f, 0.f};
    float m = -INFINITY, l = 0.f;

    // P^T shuffle lanes (verified round 4)
    const int f1l = (2 * (g & 1) + (g >> 1)) * 16 + l15;
    const int f2l = (2 * (g & 1) + 1 - (g >> 1)) * 16 + l15;
    const bool podd = (g & 1) != 0;
    const bool hbit = (g >> 1) != 0;

    int cur = 0;
    for (int t = t0; t < t1; ++t) {
        // S^T = K Q^T : st[n][r] = S^T[kv=n*16+g*4+r][q=l15]
        f32x4 st[4];
        __builtin_amdgcn_s_setprio(1);
#pragma unroll
        for (int n = 0; n < 4; ++n) {
            int kr = n * 16 + l15;
            s16x8 ka0 = *(const s16x8*)&Klds[cur][kr * 64 + (((g    ) ^ (kr & 7)) * 8)];
            s16x8 ka1 = *(const s16x8*)&Klds[cur][kr * 64 + (((g + 4) ^ (kr & 7)) * 8)];
            st[n] = __builtin_amdgcn_mfma_f32_16x16x32_bf16(ka0, qb0, f32x4{0.f,0.f,0.f,0.f}, 0, 0, 0);
            st[n] = __builtin_amdgcn_mfma_f32_16x16x32_bf16(ka1, qb1, st[n], 0, 0, 0);
        }
        __builtin_amdgcn_s_setprio(0);

        if (t == jq) {   // causal mask on diagonal tile
#pragma unroll
            for (int n = 0; n < 4; ++n)
#pragma unroll
                for (int r = 0; r < 4; ++r) {
                    int kvg = t * 64 + n * 16 + g * 4 + r;
                    if (kvg > q0w + l15) st[n][r] = -INFINITY;
                }
        }

        // row max for q=l15: in-lane 16 + xor16 + xor32
        float mt = fmaxf(fmaxf(st[0][0], st[0][1]), fmaxf(st[0][2], st[0][3]));
#pragma unroll
        for (int n = 1; n < 4; ++n)
            mt = fmaxf(mt, fmaxf(fmaxf(st[n][0], st[n][1]), fmaxf(st[n][2], st[n][3])));
        mt = fmaxf(mt, __shfl_xor(mt, 16, 64));
        mt = fmaxf(mt, __shfl_xor(mt, 32, 64));

        // defer-rescale (T13): only rescale when max grew by > 8
        if (__any(mt - m > 8.f)) {
            float mn  = fmaxf(m, mt);
            float fac = __expf(m - mn);
            m = mn;
            l *= fac;
#pragma unroll
            for (int n = 0; n < 4; ++n)
#pragma unroll
                for (int r = 0; r < 4; ++r) o[n][r] *= fac;
        }

        // P = exp(S^T - m), pack via v_cvt_pk, f32 denominator
        float rs = 0.f;
        unsigned pk[4][2];
#pragma unroll
        for (int n = 0; n < 4; ++n) {
            float p0 = __expf(st[n][0] - m);
            float p1 = __expf(st[n][1] - m);
            float p2 = __expf(st[n][2] - m);
            float p3 = __expf(st[n][3] - m);
            rs += (p0 + p1) + (p2 + p3);
            asm("v_cvt_pk_bf16_f32 %0, %1, %2" : "=v"(pk[n][0]) : "v"(p0), "v"(p1));
            asm("v_cvt_pk_bf16_f32 %0, %1, %2" : "=v"(pk[n][1]) : "v"(p2), "v"(p3));
        }
        rs += __shfl_xor(rs, 16, 64);
        rs += __shfl_xor(rs, 32, 64);
        l += rs;

        // O^T += V^T P^T ; P^T B-frag: col=q=l15, k=kv=kk*32+g*8+e
        __builtin_amdgcn_s_setprio(1);
#pragma unroll
        for (int kk = 0; kk < 2; ++kk) {
            unsigned e00 = podd ? pk[2 * kk + 1][0] : pk[2 * kk][0];
            unsigned e01 = podd ? pk[2 * kk + 1][1] : pk[2 * kk][1];
            unsigned e10 = podd ? pk[2 * kk][0]     : pk[2 * kk + 1][0];
            unsigned e11 = podd ? pk[2 * kk][1]     : pk[2 * kk + 1][1];
            unsigned x0 = (unsigned)__shfl((int)e00, f1l, 64);
            unsigned x1 = (unsigned)__shfl((int)e01, f1l, 64);
            unsigned y0 = (unsigned)__shfl((int)e10, f2l, 64);
            unsigned y1 = (unsigned)__shfl((int)e11, f2l, 64);
            unsigned w0 = hbit ? y0 : x0;
            unsigned w1 = hbit ? y1 : x1;
            unsigned w2 = hbit ? x0 : y0;
            unsigned w3 = hbit ? x1 : y1;
            u32x4 uu = { w0, w1, w2, w3 };
            s16x8 pb = __builtin_bit_cast(s16x8, uu);
#pragma unroll
            for (int n = 0; n < 4; ++n) {
                int vr = n * 16 + l15;
                s16x8 va = *(const s16x8*)&Vlds[cur][vr * 64 + (((g + kk * 4) ^ (vr & 7)) * 8)];
                o[n] = __builtin_amdgcn_mfma_f32_16x16x32_bf16(va, pb, o[n], 0, 0, 0);
            }
        }
        __builtin_amdgcn_s_setprio(0);

        // pipeline control: counted vmcnt, loads stay in flight (T4)
        if (t + 1 < t1) {
            __builtin_amdgcn_s_barrier();          // all waves done reading cur
            __builtin_amdgcn_sched_barrier(0);
            if (t + 2 < t1) {
                stageKV(cur, t + 2);               // refill cur
                asm volatile("s_waitcnt vmcnt(4)" ::: "memory");  // t+1 ready
            } else {
                asm volatile("s_waitcnt vmcnt(0)" ::: "memory");
            }
            __builtin_amdgcn_s_barrier();
            __builtin_amdgcn_sched_barrier(0);
            cur ^= 1;
        }
    }

    // epilogue: O^T partial [d][q] (coalesced), plus (m,l)
    const size_t pidx = ((size_t)b * 64 + jq) * NP + p;
    float* opb = Op + pidx * 4096;
#pragma unroll
    for (int n = 0; n < 4; ++n)
#pragma unroll
        for (int r = 0; r < 4; ++r)
            opb[(n * 16 + g * 4 + r) * 64 + w * 16 + l15] = o[n][r];
    if (lane < 16) {
        float* mlb = Ml + pidx * 128;
        mlb[w * 16 + l15]      = m;
        mlb[64 + w * 16 + l15] = l;
    }
}

// ---------------------------------------------------------------------------
// Kernel 3: merge <=8 partials per (b, q-tile) -> normalized out[q][d] fp32
// ---------------------------------------------------------------------------
__global__ __launch_bounds__(256) void attn_combine(
    const float* __restrict__ Op, const float* __restrict__ Ml,
    float* __restrict__ out)
{
    const int jq = blockIdx.x;
    const int b  = blockIdx.y;
    const int nP = (jq >> 3) + 1;
    const int tid = threadIdx.x;
    const int q  = tid & 63;
    const int dc = tid >> 6;          // 0..3
    const size_t pb = ((size_t)b * 64 + jq) * NP;

    float mv[NP], lv[NP], wt[NP];
    float mstar = -INFINITY;
#pragma unroll
    for (int p = 0; p < NP; ++p) if (p < nP) {
        mv[p] = Ml[(pb + p) * 128 + q];
        lv[p] = Ml[(pb + p) * 128 + 64 + q];
        mstar = fmaxf(mstar, mv[p]);
    }
    float L = 0.f;
#pragma unroll
    for (int p = 0; p < NP; ++p) if (p < nP) {
        wt[p] = __expf(mv[p] - mstar);
        L += lv[p] * wt[p];
    }
    float inv = 1.0f / L;

    float acc[16];
#pragma unroll
    for (int k2 = 0; k2 < 16; ++k2) acc[k2] = 0.f;
#pragma unroll
    for (int p = 0; p < NP; ++p) if (p < nP) {
        const float* src = Op + (pb + p) * 4096 + (size_t)dc * 16 * 64 + q;
#pragma unroll
        for (int k2 = 0; k2 < 16; ++k2) acc[k2] += src[k2 * 64] * wt[p];
    }
    float* dst = out + ((size_t)b * SEQ + jq * 64 + q) * HD + dc * 16;
#pragma unroll
    for (int k2 = 0; k2 < 16; ++k2) dst[k2] = acc[k2] * inv;
}

// ---------------------------------------------------------------------------
extern "C" void kernel_launch(void* const* d_in, const int* in_sizes, int n_in,
                              void* d_out, int out_size, void* d_ws, size_t ws_size,
                              hipStream_t stream)
{
    (void)in_sizes; (void)n_in; (void)out_size; (void)ws_size;
    const float* emb = (const float*)d_in[0];
    const float* wq  = (const float*)d_in[1];
    const float* wk  = (const float*)d_in[2];
    const float* wv  = (const float*)d_in[3];
    float* out = (float*)d_out;

    short* Wb = (short*)d_ws;                          // [192][1024] bf16
    short* Qb = Wb + 192 * 1024;                       // [4][4096][64] bf16
    short* Kb = Qb + (size_t)NBATCH * SEQ * HD;        // [4][4096][64] bf16
    short* Vt = Kb + (size_t)NBATCH * SEQ * HD;        // [4][64][4096] bf16
    float* Op = (float*)(Vt + (size_t)NBATCH * SEQ * HD);  // [4][64][8][64][64] f32 (O^T)
    float* Ml = Op + (size_t)NBATCH * 64 * NP * 64 * 64;   // [4][64][8][128] f32

    hipLaunchKernelGGL(prep_w, dim3(96), dim3(256), 0, stream, wq, wk, wv, Wb);
    hipLaunchKernelGGL(proj_qkv, dim3(512), dim3(256), 0, stream, emb, Wb, Qb, Kb, Vt);
    hipLaunchKernelGGL(attn_fwd, dim3(288, NBATCH), dim3(256), 0, stream,
                       Qb, Kb, Vt, Op, Ml);
    hipLaunchKernelGGL(attn_combine, dim3(64, NBATCH), dim3(256), 0, stream,
                       Op, Ml, out);
}

// Round 8
// 149.055 us; speedup vs baseline: 1.4581x; 1.0084x over previous
//
#include <hip/hip_runtime.h>
#include <hip/hip_bf16.h>

#define EMBED 1024
#define SEQ   4096
#define NBATCH 4
#define HD    64
#define CH    8    // kv tiles (of 64) per attention partition
#define NP    8    // max partitions (stride in partial buffers)

typedef __attribute__((ext_vector_type(8))) short s16x8;
typedef __attribute__((ext_vector_type(4))) float f32x4;
typedef __attribute__((ext_vector_type(4))) unsigned int u32x4;

__device__ __forceinline__ short f2bf(float f) {
    unsigned u = __builtin_bit_cast(unsigned, f);
    u += 0x7fffu + ((u >> 16) & 1u);      // round-to-nearest-even
    return (short)(u >> 16);
}

typedef const unsigned int __attribute__((address_space(1)))* gbl_ptr_t;
typedef unsigned int __attribute__((address_space(3)))* lds_ptr_t;
__device__ __forceinline__ void async16(const void* g, void* l) {
    __builtin_amdgcn_global_load_lds((gbl_ptr_t)g, (lds_ptr_t)l, 16, 0, 0);
}
// zero-cost compiler memory-reordering fence (not sched_barrier: m141)
#define MEMFENCE asm volatile("" ::: "memory")

// ---------------------------------------------------------------------------
// Kernel 0: W_Q (pre-scaled by 1/8), W_K, W_V fp32 -> bf16 Wb[192][1024]
// ---------------------------------------------------------------------------
__global__ __launch_bounds__(256) void prep_w(
    const float* __restrict__ wq, const float* __restrict__ wk,
    const float* __restrict__ wv, short* __restrict__ Wb)
{
    int idx = blockIdx.x * 256 + threadIdx.x;
    int e = idx * 8;
    int row = e >> 10, col = e & 1023;
    const float* src = (row < 64) ? (wq + (size_t)row * EMBED)
                     : (row < 128) ? (wk + (size_t)(row - 64) * EMBED)
                                   : (wv + (size_t)(row - 128) * EMBED);
    float sc = (row < 64) ? 0.125f : 1.0f;
    float4 f0 = *(const float4*)(src + col);
    float4 f1 = *(const float4*)(src + col + 4);
    s16x8 v = { f2bf(f0.x*sc), f2bf(f0.y*sc), f2bf(f0.z*sc), f2bf(f0.w*sc),
                f2bf(f1.x*sc), f2bf(f1.y*sc), f2bf(f1.z*sc), f2bf(f1.w*sc) };
    *(s16x8*)&Wb[e] = v;
}

// ---------------------------------------------------------------------------
// Kernel 1: QKV projection. BM=32, BN=192, BK=64; 512 blocks x 4 waves.
// Counted-vmcnt pipeline; raw s_barrier + zero-cost memory fences.
// ---------------------------------------------------------------------------
__global__ __launch_bounds__(256) void proj_qkv(
    const float* __restrict__ emb, const short* __restrict__ Wb,
    short* __restrict__ Qb, short* __restrict__ Kb, short* __restrict__ Vt)
{
    __shared__ short Alds[2][32 * 64];    // 2 x 4 KB
    __shared__ short Blds[2][192 * 64];   // 2 x 24 KB

    const int tid  = threadIdx.x;
    const int lane = tid & 63;
    const int w    = tid >> 6;
    const int wr   = w & 1;
    const int wc   = w >> 1;
    const int row0 = blockIdx.x * 32;

    const int sr   = tid >> 3;     // staging row 0..31
    const int sg   = tid & 7;      // 16B group 0..7
    const int srow = lane >> 3;
    const int sblk = lane & 7;

    f32x4 acc[6];
#pragma unroll
    for (int i = 0; i < 6; ++i) acc[i] = f32x4{0.f, 0.f, 0.f, 0.f};

    auto stageB = [&](int buf, int t) {
        const int k0 = t * 64;
#pragma unroll
        for (int i = 0; i < 6; ++i) {
            int r = w * 48 + i * 8 + srow;
            async16(Wb + (size_t)r * EMBED + k0 + ((sblk ^ (r & 7)) * 8),
                    &Blds[buf][(w * 48 + i * 8) * 64]);
        }
    };
    const float* abase = emb + (size_t)(row0 + sr) * EMBED + sg * 8;
    auto writeA = [&](int buf, float4 f0, float4 f1) {
        s16x8 v = { f2bf(f0.x), f2bf(f0.y), f2bf(f0.z), f2bf(f0.w),
                    f2bf(f1.x), f2bf(f1.y), f2bf(f1.z), f2bf(f1.w) };
        *(s16x8*)&Alds[buf][sr * 64 + ((sg ^ (sr & 7)) * 8)] = v;
    };

    // prologue
    float4 f0a = *(const float4*)(abase);
    float4 f1a = *(const float4*)(abase + 4);
    stageB(0, 0);                     // 6 async16
    writeA(0, f0a, f1a);
    f0a = *(const float4*)(abase + 64);
    f1a = *(const float4*)(abase + 68);
    stageB(1, 1);                     // outstanding: B0(6)+B1(6)
    asm volatile("s_waitcnt vmcnt(8) lgkmcnt(0)" ::: "memory");  // B0 + A-write done
    __builtin_amdgcn_s_barrier();
    MEMFENCE;

    int cur = 0;
    const int ar = wr * 16 + (lane & 15);
    const int ag = lane >> 4;

    for (int t = 0; t < 16; ++t) {
        s16x8 a0 = *(const s16x8*)&Alds[cur][ar * 64 + (((ag    ) ^ (ar & 7)) * 8)];
        s16x8 a1 = *(const s16x8*)&Alds[cur][ar * 64 + (((ag + 4) ^ (ar & 7)) * 8)];
#pragma unroll
        for (int n = 0; n < 6; ++n) {
            int br = wc * 96 + n * 16 + (lane & 15);
            s16x8 b0 = *(const s16x8*)&Blds[cur][br * 64 + (((ag    ) ^ (br & 7)) * 8)];
            s16x8 b1 = *(const s16x8*)&Blds[cur][br * 64 + (((ag + 4) ^ (br & 7)) * 8)];
            acc[n] = __builtin_amdgcn_mfma_f32_16x16x32_bf16(a0, b0, acc[n], 0, 0, 0);
            acc[n] = __builtin_amdgcn_mfma_f32_16x16x32_bf16(a1, b1, acc[n], 0, 0, 0);
        }
        if (t == 15) break;

        __builtin_amdgcn_s_barrier();          // all waves done reading cur
        MEMFENCE;
        writeA(cur ^ 1, f0a, f1a);             // A(t+1) -> nxt
        if (t < 14) {
            f0a = *(const float4*)(abase + (size_t)(t + 2) * 64);
            f1a = *(const float4*)(abase + (size_t)(t + 2) * 64 + 4);
            stageB(cur, t + 2);                // B(t+2) -> cur
            asm volatile("s_waitcnt vmcnt(8) lgkmcnt(0)" ::: "memory"); // B(t+1) done
        } else {
            asm volatile("s_waitcnt vmcnt(0) lgkmcnt(0)" ::: "memory");
        }
        __builtin_amdgcn_s_barrier();
        MEMFENCE;
        cur ^= 1;
    }

    // epilogue: C layout col=lane&15, row=(lane>>4)*4+reg
    const int rbase = row0 + wr * 16 + ((lane >> 4) * 4);
    const int cl = lane & 15;
#pragma unroll
    for (int n = 0; n < 6; ++n) {
        int col = wc * 96 + n * 16 + cl;
        int mat = col >> 6;
        int c = col & 63;
#pragma unroll
        for (int r = 0; r < 4; ++r) {
            int row = rbase + r;
            int b = row >> 12, s = row & 4095;
            short v = f2bf(acc[n][r]);
            if (mat == 0)       Qb[((size_t)b * SEQ + s) * HD + c] = v;
            else if (mat == 1)  Kb[((size_t)b * SEQ + s) * HD + c] = v;
            else                Vt[((size_t)b * HD + c) * SEQ + s] = v;
        }
    }
}

// ---------------------------------------------------------------------------
// Kernel 2: causal flash attention, QBLK=128 (8 waves x 16 q rows).
// Exact triangular grid: 144 (jq,p) pairs per batch, longest-first.
// Counted-vmcnt double-buffered K/V staging; swapped-QK in-register softmax;
// 8-bpermute P^T assembly (r4-verified); defer-rescale; setprio.
// ---------------------------------------------------------------------------
__global__ __launch_bounds__(512) void attn_fwd(
    const short* __restrict__ Qb, const short* __restrict__ Kb,
    const short* __restrict__ Vt, float* __restrict__ Op, float* __restrict__ Ml)
{
    const int b = blockIdx.y;
    // invert band index: i in [0,144): band a = jq>>2 has 4 jq x (a+1) p's.
    const int i = 143 - blockIdx.x;            // descending work order
    int a = (int)((sqrtf((float)(1 + 2 * i)) - 1.0f) * 0.5f);
    while (2 * (a + 1) * (a + 2) <= i) ++a;
    while (2 * a * (a + 1) > i) --a;
    const int rem = i - 2 * a * (a + 1);
    const int ap1 = a + 1;
    const int r_  = rem / ap1;
    const int jq  = 4 * a + r_;                // 128-row q-tile 0..31
    const int p   = rem - r_ * ap1;            // partition 0..a
    const int t0  = p * CH;
    const int t1  = min(t0 + CH, 2 * jq + 2);

    __shared__ short Klds[2][64 * 64];     // 16 KB [kv][d] swizzled
    __shared__ short Vlds[2][64 * 64];     // 16 KB [d][kv] swizzled

    const int tid  = threadIdx.x;
    const int lane = tid & 63;
    const int w    = tid >> 6;             // 0..7
    const int l15  = lane & 15;
    const int g    = lane >> 4;
    const int q0w  = jq * 128 + w * 16;

    const short* Kbase0 = Kb + (size_t)b * SEQ * HD;
    const short* Vbase0 = Vt + (size_t)b * HD * SEQ;

    const int srow = lane >> 3;
    const int sblk = lane & 7;

    auto stageKV = [&](int buf, int t) {   // 2 async16 per wave (8 rows each)
        const int kv0 = t * 64;
        int r = w * 8 + srow;
        async16(Kbase0 + (size_t)(kv0 + r) * HD + ((sblk ^ (r & 7)) * 8),
                &Klds[buf][(w * 8) * 64]);
        async16(Vbase0 + (size_t)r * SEQ + kv0 + ((sblk ^ (r & 7)) * 8),
                &Vlds[buf][(w * 8) * 64]);
    };

    // Q B-frags direct from global (coalesced)
    const short* qp = Qb + ((size_t)b * SEQ + q0w + l15) * HD + g * 8;
    s16x8 qb0 = *(const s16x8*)qp;
    s16x8 qb1 = *(const s16x8*)(qp + 32);

    stageKV(0, t0);
    if (t0 + 1 < t1) {
        stageKV(1, t0 + 1);
        asm volatile("s_waitcnt vmcnt(2)" ::: "memory");  // buf0 ready
    } else {
        asm volatile("s_waitcnt vmcnt(0)" ::: "memory");
    }
    __builtin_amdgcn_s_barrier();
    MEMFENCE;

    f32x4 o[4];
#pragma unroll
    for (int n = 0; n < 4; ++n) o[n] = f32x4{0.f, 0.f, 0.f, 0.f};
    float m = -INFINITY, l = 0.f;

    // P^T shuffle lanes (verified round 4)
    const int f1l = (2 * (g & 1) + (g >> 1)) * 16 + l15;
    const int f2l = (2 * (g & 1) + 1 - (g >> 1)) * 16 + l15;
    const bool podd = (g & 1) != 0;
    const bool hbit = (g >> 1) != 0;

    int cur = 0;
    for (int t = t0; t < t1; ++t) {
        // S^T = K Q^T : st[n][r] = S^T[kv=n*16+g*4+r][q=l15]
        f32x4 st[4];
        __builtin_amdgcn_s_setprio(1);
#pragma unroll
        for (int n = 0; n < 4; ++n) {
            int kr = n * 16 + l15;
            s16x8 ka0 = *(const s16x8*)&Klds[cur][kr * 64 + (((g    ) ^ (kr & 7)) * 8)];
            s16x8 ka1 = *(const s16x8*)&Klds[cur][kr * 64 + (((g + 4) ^ (kr & 7)) * 8)];
            st[n] = __builtin_amdgcn_mfma_f32_16x16x32_bf16(ka0, qb0, f32x4{0.f,0.f,0.f,0.f}, 0, 0, 0);
            st[n] = __builtin_amdgcn_mfma_f32_16x16x32_bf16(ka1, qb1, st[n], 0, 0, 0);
        }
        __builtin_amdgcn_s_setprio(0);

        if (t * 64 + 63 > q0w) {   // causal mask (any masked kv for this wave)
#pragma unroll
            for (int n = 0; n < 4; ++n)
#pragma unroll
                for (int r2 = 0; r2 < 4; ++r2) {
                    int kvg = t * 64 + n * 16 + g * 4 + r2;
                    if (kvg > q0w + l15) st[n][r2] = -INFINITY;
                }
        }

        // row max for q=l15: in-lane 16 + xor16 + xor32
        float mt = fmaxf(fmaxf(st[0][0], st[0][1]), fmaxf(st[0][2], st[0][3]));
#pragma unroll
        for (int n = 1; n < 4; ++n)
            mt = fmaxf(mt, fmaxf(fmaxf(st[n][0], st[n][1]), fmaxf(st[n][2], st[n][3])));
        mt = fmaxf(mt, __shfl_xor(mt, 16, 64));
        mt = fmaxf(mt, __shfl_xor(mt, 32, 64));

        // defer-rescale (T13): only rescale when max grew by > 8
        if (__any(mt - m > 8.f)) {
            float mn  = fmaxf(m, mt);
            float fac = __expf(m - mn);
            m = mn;
            l *= fac;
#pragma unroll
            for (int n = 0; n < 4; ++n)
#pragma unroll
                for (int r2 = 0; r2 < 4; ++r2) o[n][r2] *= fac;
        }

        // P = exp(S^T - m), pack via v_cvt_pk, f32 denominator
        float rs = 0.f;
        unsigned pk[4][2];
#pragma unroll
        for (int n = 0; n < 4; ++n) {
            float p0 = __expf(st[n][0] - m);
            float p1 = __expf(st[n][1] - m);
            float p2 = __expf(st[n][2] - m);
            float p3 = __expf(st[n][3] - m);
            rs += (p0 + p1) + (p2 + p3);
            asm("v_cvt_pk_bf16_f32 %0, %1, %2" : "=v"(pk[n][0]) : "v"(p0), "v"(p1));
            asm("v_cvt_pk_bf16_f32 %0, %1, %2" : "=v"(pk[n][1]) : "v"(p2), "v"(p3));
        }
        rs += __shfl_xor(rs, 16, 64);
        rs += __shfl_xor(rs, 32, 64);
        l += rs;

        // O^T += V^T P^T ; P^T B-frag: col=q=l15, k=kv=kk*32+g*8+e
        __builtin_amdgcn_s_setprio(1);
#pragma unroll
        for (int kk = 0; kk < 2; ++kk) {
            unsigned e00 = podd ? pk[2 * kk + 1][0] : pk[2 * kk][0];
            unsigned e01 = podd ? pk[2 * kk + 1][1] : pk[2 * kk][1];
            unsigned e10 = podd ? pk[2 * kk][0]     : pk[2 * kk + 1][0];
            unsigned e11 = podd ? pk[2 * kk][1]     : pk[2 * kk + 1][1];
            unsigned x0 = (unsigned)__shfl((int)e00, f1l, 64);
            unsigned x1 = (unsigned)__shfl((int)e01, f1l, 64);
            unsigned y0 = (unsigned)__shfl((int)e10, f2l, 64);
            unsigned y1 = (unsigned)__shfl((int)e11, f2l, 64);
            unsigned w0 = hbit ? y0 : x0;
            unsigned w1 = hbit ? y1 : x1;
            unsigned w2 = hbit ? x0 : y0;
            unsigned w3 = hbit ? x1 : y1;
            u32x4 uu = { w0, w1, w2, w3 };
            s16x8 pb = __builtin_bit_cast(s16x8, uu);
#pragma unroll
            for (int n = 0; n < 4; ++n) {
                int vr = n * 16 + l15;
                s16x8 va = *(const s16x8*)&Vlds[cur][vr * 64 + (((g + kk * 4) ^ (vr & 7)) * 8)];
                o[n] = __builtin_amdgcn_mfma_f32_16x16x32_bf16(va, pb, o[n], 0, 0, 0);
            }
        }
        __builtin_amdgcn_s_setprio(0);

        // pipeline control: counted vmcnt, loads stay in flight (T4)
        if (t + 1 < t1) {
            __builtin_amdgcn_s_barrier();          // all waves done reading cur
            MEMFENCE;
            if (t + 2 < t1) {
                stageKV(cur, t + 2);               // refill cur
                asm volatile("s_waitcnt vmcnt(2)" ::: "memory");  // t+1 ready
            } else {
                asm volatile("s_waitcnt vmcnt(0)" ::: "memory");
            }
            __builtin_amdgcn_s_barrier();
            MEMFENCE;
            cur ^= 1;
        }
    }

    // epilogue: O^T partial [d=64][q=128] (coalesced), plus (m,l)
    const size_t pidx = ((size_t)b * 32 + jq) * NP + p;
    float* opb = Op + pidx * 8192;
#pragma unroll
    for (int n = 0; n < 4; ++n)
#pragma unroll
        for (int r2 = 0; r2 < 4; ++r2)
            opb[(n * 16 + g * 4 + r2) * 128 + w * 16 + l15] = o[n][r2];
    if (lane < 16) {
        float* mlb = Ml + pidx * 256;
        mlb[w * 16 + l15]       = m;
        mlb[128 + w * 16 + l15] = l;
    }
}

// ---------------------------------------------------------------------------
// Kernel 3: merge <=8 partials per (b, 128-q tile) -> normalized out[q][d]
// ---------------------------------------------------------------------------
__global__ __launch_bounds__(256) void attn_combine(
    const float* __restrict__ Op, const float* __restrict__ Ml,
    float* __restrict__ out)
{
    const int jq = blockIdx.x;        // 0..31
    const int b  = blockIdx.y;
    const int nP = (jq >> 2) + 1;
    const int tid = threadIdx.x;
    const int q  = tid & 127;
    const int dc = tid >> 7;          // 0..1 (32 d each)
    const size_t pb = ((size_t)b * 32 + jq) * NP;

    float mv[NP], lv[NP], wt[NP];
    float mstar = -INFINITY;
#pragma unroll
    for (int p = 0; p < NP; ++p) if (p < nP) {
        mv[p] = Ml[(pb + p) * 256 + q];
        lv[p] = Ml[(pb + p) * 256 + 128 + q];
        mstar = fmaxf(mstar, mv[p]);
    }
    float L = 0.f;
#pragma unroll
    for (int p = 0; p < NP; ++p) if (p < nP) {
        wt[p] = __expf(mv[p] - mstar);
        L += lv[p] * wt[p];
    }
    float inv = 1.0f / L;

    float acc[32];
#pragma unroll
    for (int k2 = 0; k2 < 32; ++k2) acc[k2] = 0.f;
#pragma unroll
    for (int p = 0; p < NP; ++p) if (p < nP) {
        const float* src = Op + (pb + p) * 8192 + (size_t)dc * 32 * 128 + q;
#pragma unroll
        for (int k2 = 0; k2 < 32; ++k2) acc[k2] += src[k2 * 128] * wt[p];
    }
    float* dst = out + ((size_t)b * SEQ + jq * 128 + q) * HD + dc * 32;
#pragma unroll
    for (int k2 = 0; k2 < 32; ++k2) dst[k2] = acc[k2] * inv;
}

// ---------------------------------------------------------------------------
extern "C" void kernel_launch(void* const* d_in, const int* in_sizes, int n_in,
                              void* d_out, int out_size, void* d_ws, size_t ws_size,
                              hipStream_t stream)
{
    (void)in_sizes; (void)n_in; (void)out_size; (void)ws_size;
    const float* emb = (const float*)d_in[0];
    const float* wq  = (const float*)d_in[1];
    const float* wk  = (const float*)d_in[2];
    const float* wv  = (const float*)d_in[3];
    float* out = (float*)d_out;

    short* Wb = (short*)d_ws;                          // [192][1024] bf16
    short* Qb = Wb + 192 * 1024;                       // [4][4096][64] bf16
    short* Kb = Qb + (size_t)NBATCH * SEQ * HD;        // [4][4096][64] bf16
    short* Vt = Kb + (size_t)NBATCH * SEQ * HD;        // [4][64][4096] bf16
    float* Op = (float*)(Vt + (size_t)NBATCH * SEQ * HD);  // [4][32][8][64][128] f32
    float* Ml = Op + (size_t)NBATCH * 32 * NP * 8192;      // [4][32][8][256] f32

    hipLaunchKernelGGL(prep_w, dim3(96), dim3(256), 0, stream, wq, wk, wv, Wb);
    hipLaunchKernelGGL(proj_qkv, dim3(512), dim3(256), 0, stream, emb, Wb, Qb, Kb, Vt);
    hipLaunchKernelGGL(attn_fwd, dim3(144, NBATCH), dim3(512), 0, stream,
                       Qb, Kb, Vt, Op, Ml);
    hipLaunchKernelGGL(attn_combine, dim3(32, NBATCH), dim3(256), 0, stream,
                       Op, Ml, out);
}